// Round 8
// baseline (5999.568 us; speedup 1.0000x reference)
//
#include <hip/hip_runtime.h>

#define Hd 256
#define Wd 256
#define HW 65536
#define C 64
#define B 8
#define M 16
#define NDEPTH 4
#define NMLP 128

// ---------------- twiddle table: e^{2*pi*i*t/256}, double-precision accurate --------------
__global__ void k_table(float2* __restrict__ tab) {
    int t = threadIdx.x;
    double a = (6.283185307179586476925286766559 / 256.0) * (double)t;
    tab[t] = make_float2((float)cos(a), (float)sin(a));
}

// ---------------- fc0: 3 -> 64 channels, per pixel ----------------
__global__ void k_fc0(const float* __restrict__ x, const float* __restrict__ w,
                      const float* __restrict__ bias, float* __restrict__ h) {
    int p = blockIdx.x * 256 + threadIdx.x;   // 0 .. B*HW-1
    int b = p >> 16, pix = p & 65535;
    float x0 = x[(b * 3 + 0) * HW + pix];
    float x1 = x[(b * 3 + 1) * HW + pix];
    float x2 = x[(b * 3 + 2) * HW + pix];
    for (int o = 0; o < C; ++o) {
        float v = bias[o];
        v = fmaf(w[o * 3 + 0], x0, v);
        v = fmaf(w[o * 3 + 1], x1, v);
        v = fmaf(w[o * 3 + 2], x2, v);
        h[(b * C + o) * HW + pix] = v;
    }
}

// ---------------- forward DFT along y: T1[bc,ky,w] = sum_y h[bc,y,w] e^{-2pi i ky y/256} ---
__global__ __launch_bounds__(256, 2)
void k_fwd_y(const float* __restrict__ h, const float2* __restrict__ tab,
             float2* __restrict__ T1) {
    __shared__ float2 st[256];
    int bc = blockIdx.x;          // b*C+c
    int w = threadIdx.x;          // 0..255
    st[w] = tab[w];
    __syncthreads();
    const float* hp = h + bc * HW + w;
    float ar[M], ai[M];
#pragma unroll
    for (int k = 0; k < M; ++k) { ar[k] = 0.f; ai[k] = 0.f; }
    for (int y = 0; y < Hd; ++y) {
        float v = hp[y * Wd];
#pragma unroll
        for (int k = 0; k < M; ++k) {
            float2 e = st[(k * y) & 255];    // uniform LDS broadcast, in-order
            ar[k] = fmaf(v, e.x, ar[k]);
            ai[k] = fmaf(v, -e.y, ai[k]);
        }
    }
    float2* out = T1 + bc * (M * Wd) + w;
#pragma unroll
    for (int k = 0; k < M; ++k) out[k * Wd] = make_float2(ar[k], ai[k]);
}

// ---------------- forward DFT along x: X[bc, ky*16+kx] = sum_w T1[bc,ky,w] e^{-2pi i kx w/256}
__global__ __launch_bounds__(256, 2)
void k_fwd_x(const float2* __restrict__ T1, const float2* __restrict__ tab,
             float2* __restrict__ X) {
    __shared__ float2 sT[M * Wd];   // 32 KB
    __shared__ float2 st[256];      // 2 KB
    int bc = blockIdx.x, t = threadIdx.x;
    const float2* src = T1 + bc * (M * Wd);
#pragma unroll
    for (int j = 0; j < M; ++j) sT[j * 256 + t] = src[j * 256 + t];
    st[t] = tab[t];
    __syncthreads();
    int ky = t >> 4, kx = t & 15;
    float xr0 = 0.f, xi0 = 0.f, xr1 = 0.f, xi1 = 0.f;
    for (int w = 0; w < Wd; w += 2) {
        float2 Ta = sT[ky * 256 + w];
        float2 ea = st[(kx * w) & 255];
        xr0 = fmaf(Ta.x, ea.x, fmaf(Ta.y, ea.y, xr0));
        xi0 = fmaf(Ta.y, ea.x, fmaf(-Ta.x, ea.y, xi0));
        float2 Tb = sT[ky * 256 + w + 1];
        float2 eb = st[(kx * (w + 1)) & 255];
        xr1 = fmaf(Tb.x, eb.x, fmaf(Tb.y, eb.y, xr1));
        xi1 = fmaf(Tb.y, eb.x, fmaf(-Tb.x, eb.y, xi1));
    }
    X[bc * 256 + t] = make_float2(xr0 + xr1, xi0 + xi1);
}

// ---------------- mode mixing: Y[b,o,m] = sum_i X[b,i,m] * (wre+j*wim)[i,o,m] -------------
__global__ __launch_bounds__(256, 2)
void k_mix(const float2* __restrict__ X, const float* __restrict__ wre,
           const float* __restrict__ wim, float2* __restrict__ Y) {
    int o = blockIdx.x >> 2;   // 0..63
    int bq = blockIdx.x & 3;   // pair of batches
    int m = threadIdx.x;       // mode = ky*16+kx
    int b0 = bq * 2, b1 = bq * 2 + 1;
    float yr0 = 0.f, yi0 = 0.f, yr1 = 0.f, yi1 = 0.f;
    for (int i = 0; i < C; ++i) {
        float wr = wre[(i * C + o) * 256 + m];
        float wi = wim[(i * C + o) * 256 + m];
        float2 x0 = X[(b0 * C + i) * 256 + m];
        float2 x1 = X[(b1 * C + i) * 256 + m];
        yr0 = fmaf(x0.x, wr, fmaf(-x0.y, wi, yr0));
        yi0 = fmaf(x0.x, wi, fmaf(x0.y, wr, yi0));
        yr1 = fmaf(x1.x, wr, fmaf(-x1.y, wi, yr1));
        yi1 = fmaf(x1.x, wi, fmaf(x1.y, wr, yi1));
    }
    Y[(b0 * C + o) * 256 + m] = make_float2(yr0, yi0);
    Y[(b1 * C + o) * 256 + m] = make_float2(yr1, yi1);
}

// ---------------- inverse along y (with 1/(H*W) and Hermitian x2 folded in) ---------------
// G[bc, y, kx] = scale(kx) * sum_ky Y[bc, ky*16+kx] e^{+2pi i ky y/256}
__global__ __launch_bounds__(256, 2)
void k_inv_y(const float2* __restrict__ Y, const float2* __restrict__ tab,
             float2* __restrict__ G) {
    __shared__ float2 sY[256];
    __shared__ float2 st[256];
    int bc = blockIdx.x, t = threadIdx.x;   // t = y
    sY[t] = Y[bc * 256 + t];
    st[t] = tab[t];
    __syncthreads();
    float2 out[M];
#pragma unroll
    for (int kx = 0; kx < M; ++kx) {
        float gr = 0.f, gi = 0.f;
#pragma unroll
        for (int ky = 0; ky < M; ++ky) {
            float2 yv = sY[ky * 16 + kx];
            float2 e = st[(ky * t) & 255];
            gr = fmaf(yv.x, e.x, fmaf(-yv.y, e.y, gr));
            gi = fmaf(yv.x, e.y, fmaf(yv.y, e.x, gi));
        }
        float sc = (kx == 0 ? 1.0f : 2.0f) * (1.0f / 65536.0f);
        out[kx] = make_float2(gr * sc, gi * sc);
    }
    float2* gp = G + (bc * 256 + t) * M;
#pragma unroll
    for (int kx = 0; kx < M; ++kx) gp[kx] = out[kx];
}

// ---------------- fused: inverse along x + conv1x1 + add + relu, in-place on h ------------
// R8: back to the proven 1-px/thread R5 body (>128-VGPR designs spill — R6/R7 lesson:
// the toolchain won't grant more than a 128-reg budget). __launch_bounds__(256,4):
// cap 128 >= the ~116 this body needs, and 4 blocks/CU (LDS 34.8 KB fits 4) doubles
// resident waves vs (256,2) to hide the per-o LDS-broadcast latency (R5 gap between
// 183 us measured and ~50 us issue model = latency stalls).
__global__ __launch_bounds__(256, 4)
void k_final(float* __restrict__ h, const float2* __restrict__ G,
             const float* __restrict__ ww, const float* __restrict__ wb,
             const float2* __restrict__ tab) {
    __shared__ float4 sW[C * 16];   // 16 KB: ww[o][i] as 16 float4 per o
    __shared__ float2 sG[C * M];    // 8 KB, [o][k]
    __shared__ float2 st[256];      // 2 KB
    __shared__ float  sB[C];        // 256 B
    int by = blockIdx.x;
    int b = by >> 8, y = by & 255;
    int x = threadIdx.x;
    st[x] = tab[x];
    {   // stage ww: 1024 float4, coalesced
        const float4* wf4 = (const float4*)ww;
#pragma unroll
        for (int p = 0; p < 4; ++p) sW[x + p * 256] = wf4[x + p * 256];
    }
    if (x < C) sB[x] = wb[x];
    {   // stage G slice: 512 float4; threads f=8o..8o+7 fetch one 128 B row (coalesced)
        const float4* Gf4 = (const float4*)G;
        float4* sGf4 = (float4*)sG;
        int f0 = x, o0 = f0 >> 3, q0 = f0 & 7;
        sGf4[f0] = Gf4[((size_t)(b * C + o0) * 256 + y) * 8 + q0];
        int f1 = x + 256, o1 = f1 >> 3, q1 = f1 & 7;
        sGf4[f1] = Gf4[((size_t)(b * C + o1) * 256 + y) * 8 + q1];
    }
    __syncthreads();
    float cs[M], sn[M];
#pragma unroll
    for (int k = 0; k < M; ++k) {
        float2 e = st[(k * x) & 255];
        cs[k] = e.x; sn[k] = e.y;
    }
    float hp[C];
    float* hb = h + b * C * HW + y * Wd + x;
#pragma unroll
    for (int i = 0; i < C; ++i) hp[i] = hb[i * HW];
    const float4* sG4 = (const float4*)sG;
    for (int o = 0; o < C; ++o) {
        float a0 = sB[o], a1 = 0.f, a2 = 0.f, a3 = 0.f;
#pragma unroll
        for (int c = 0; c < 16; ++c) {
            float4 wv = sW[o * 16 + c];      // broadcast ds_read_b128, in-order
            a0 = fmaf(wv.x, hp[4 * c + 0], a0);
            a1 = fmaf(wv.y, hp[4 * c + 1], a1);
            a2 = fmaf(wv.z, hp[4 * c + 2], a2);
            a3 = fmaf(wv.w, hp[4 * c + 3], a3);
        }
#pragma unroll
        for (int q = 0; q < 8; ++q) {
            float4 g = sG4[o * 8 + q];       // (re,im,re,im) for k=2q,2q+1
            a0 = fmaf(g.x, cs[2 * q], a0);
            a1 = fmaf(-g.y, sn[2 * q], a1);
            a2 = fmaf(g.z, cs[2 * q + 1], a2);
            a3 = fmaf(-g.w, sn[2 * q + 1], a3);
        }
        hb[o * HW] = fmaxf((a0 + a1) + (a2 + a3), 0.0f);
    }
}

// ---------------- fused fc1 (relu) + fc2, per pixel ----------------
// R8: R5 body + VOLATILE hp loads. R5 showed VGPR=68 + VALUBusy 83%: the allocator
// rematerialized hp[] by re-loading from global inside the m-loop (no scratch writes,
// L2-absorbed re-reads, massive VALU bloat). volatile loads cannot be duplicated ->
// hp must stay resident (~90 regs, fits the 128 budget of (256,4)).
__global__ __launch_bounds__(256, 4)
void k_fc12(const float* __restrict__ h, const float* __restrict__ w1,
            const float* __restrict__ b1, const float* __restrict__ w2,
            const float* __restrict__ b2, float* __restrict__ out) {
    __shared__ float4 sW1[NMLP * 16];   // 32 KB
    __shared__ float  sB1[NMLP];        // 512 B
    __shared__ float  sW2[3 * NMLP];    // 1.5 KB
    int by = blockIdx.x;
    int b = by >> 8, y = by & 255;
    int x = threadIdx.x;
    {   // stage w1: 2048 float4, coalesced
        const float4* wf4 = (const float4*)w1;
#pragma unroll
        for (int p = 0; p < 8; ++p) sW1[x + p * 256] = wf4[x + p * 256];
    }
    if (x < NMLP) sB1[x] = b1[x];
    sW2[x] = w2[x];
    if (x < 3 * NMLP - 256) sW2[256 + x] = w2[256 + x];
    __syncthreads();
    const volatile float* hb = h + b * C * HW + y * Wd + x;   // volatile: no remat
    float hp[C];
#pragma unroll
    for (int i = 0; i < C; ++i) hp[i] = hb[i * HW];
    float a0 = b2[0], a1 = b2[1], a2 = b2[2];
    for (int m = 0; m < NMLP; ++m) {
        float c0 = sB1[m], c1 = 0.f, c2 = 0.f, c3 = 0.f;
#pragma unroll
        for (int c = 0; c < 16; ++c) {
            float4 wv = sW1[m * 16 + c];    // broadcast ds_read_b128
            c0 = fmaf(wv.x, hp[4 * c + 0], c0);
            c1 = fmaf(wv.y, hp[4 * c + 1], c1);
            c2 = fmaf(wv.z, hp[4 * c + 2], c2);
            c3 = fmaf(wv.w, hp[4 * c + 3], c3);
        }
        float acc = fmaxf((c0 + c1) + (c2 + c3), 0.0f);
        a0 = fmaf(sW2[0 * NMLP + m], acc, a0);
        a1 = fmaf(sW2[1 * NMLP + m], acc, a1);
        a2 = fmaf(sW2[2 * NMLP + m], acc, a2);
    }
    float* ob = out + b * 3 * HW + y * Wd + x;
    ob[0] = a0;
    ob[HW] = a1;
    ob[2 * HW] = a2;
}

extern "C" void kernel_launch(void* const* d_in, const int* in_sizes, int n_in,
                              void* d_out, int out_size, void* d_ws, size_t ws_size,
                              hipStream_t stream) {
    const float* x     = (const float*)d_in[0];
    const float* fc0_w = (const float*)d_in[1];
    const float* fc0_b = (const float*)d_in[2];
    const float* swre  = (const float*)d_in[3];   // [4,64,64,16,16]
    const float* swim  = (const float*)d_in[4];
    const float* ww    = (const float*)d_in[5];   // [4,64,64]
    const float* wb    = (const float*)d_in[6];   // [4,64]
    const float* fc1w  = (const float*)d_in[7];
    const float* fc1b  = (const float*)d_in[8];
    const float* fc2w  = (const float*)d_in[9];
    const float* fc2b  = (const float*)d_in[10];

    float* ws = (float*)d_ws;
    float2* tab = (float2*)ws;                               // 512 floats
    float*  h   = ws + 512;                                  // 33,554,432 floats
    float2* T1  = (float2*)(ws + 512 + 33554432);            // 4,194,304 floats (doubles as G)
    float2* X   = (float2*)(ws + 512 + 33554432 + 4194304);  // 262,144 floats
    float2* Y   = (float2*)(ws + 512 + 33554432 + 4194304 + 262144); // 262,144 floats

    k_table<<<dim3(1), dim3(256), 0, stream>>>(tab);
    k_fc0<<<dim3(2048), dim3(256), 0, stream>>>(x, fc0_w, fc0_b, h);

    for (int d = 0; d < NDEPTH; ++d) {
        k_fwd_y<<<dim3(512), dim3(256), 0, stream>>>(h, tab, T1);
        k_fwd_x<<<dim3(512), dim3(256), 0, stream>>>(T1, tab, X);
        k_mix<<<dim3(256), dim3(256), 0, stream>>>(X, swre + (size_t)d * C * C * 256,
                                                   swim + (size_t)d * C * C * 256, Y);
        k_inv_y<<<dim3(512), dim3(256), 0, stream>>>(Y, tab, T1 /* reused as G */);
        k_final<<<dim3(2048), dim3(256), 0, stream>>>(h, T1, ww + d * C * C, wb + d * C, tab);
    }
    k_fc12<<<dim3(2048), dim3(256), 0, stream>>>(h, fc1w, fc1b, fc2w, fc2b, (float*)d_out);
}

// Round 9
// 1201.810 us; speedup vs baseline: 4.9921x; 4.9921x over previous
//
#include <hip/hip_runtime.h>

#define Hd 256
#define Wd 256
#define HW 65536
#define C 64
#define B 8
#define M 16
#define NDEPTH 4
#define NMLP 128

// ---------------- twiddle table: e^{2*pi*i*t/256}, double-precision accurate --------------
__global__ void k_table(float2* __restrict__ tab) {
    int t = threadIdx.x;
    double a = (6.283185307179586476925286766559 / 256.0) * (double)t;
    tab[t] = make_float2((float)cos(a), (float)sin(a));
}

// ---------------- once: trig planes (32x256) + fc1w^T (64x128) ----------------
// trig[kk][x] = cos(2pi kk x/256) for kk<16, sin(2pi (kk-16) x/256) for kk>=16.
__global__ void k_prep0(const float2* __restrict__ tab, const float* __restrict__ fc1w,
                        float* __restrict__ trig, float* __restrict__ w1T) {
    int blk = blockIdx.x, t = threadIdx.x;
    if (blk < 32) {
        int k = blk & 15;
        float2 e = tab[(k * t) & 255];
        trig[blk * 256 + t] = (blk < 16) ? e.x : e.y;
    } else {
        int f = (blk - 32) * 256 + t;    // 0..16383
        int i = f >> 7, m = f & 127;
        w1T[i * 128 + m] = fc1w[m * 64 + i];
    }
}

// ---------------- per layer: ww^T (64x64) + Gq[b,y][kk][o] (2048x32x64) ----------------
// Gq row kk<16 = Re(G[o][kk]); kk>=16 = -Im(G[o][kk-16]).  Coalesced writes.
__global__ void k_prep(const float2* __restrict__ G, const float* __restrict__ ww,
                       float* __restrict__ Gq, float* __restrict__ wwT) {
    int blk = blockIdx.x, t = threadIdx.x;
    if (blk < 2048) {
        int b = blk >> 8, y = blk & 255;
#pragma unroll
        for (int p = 0; p < 8; ++p) {
            int f = t + p * 256;           // 0..2047
            int kk = f >> 6, o = f & 63;
            float2 g = G[((size_t)(b * 64 + o) * 256 + y) * 16 + (kk & 15)];
            Gq[((size_t)(b * 256 + y) * 32 + kk) * 64 + o] = (kk < 16) ? g.x : -g.y;
        }
    } else {
        int f = (blk - 2048) * 256 + t;    // 0..4095
        int i = f >> 6, o = f & 63;
        wwT[i * 64 + o] = ww[o * 64 + i];
    }
}

// ---------------- fc0: 3 -> 64 channels, per pixel ----------------
__global__ void k_fc0(const float* __restrict__ x, const float* __restrict__ w,
                      const float* __restrict__ bias, float* __restrict__ h) {
    int p = blockIdx.x * 256 + threadIdx.x;
    int b = p >> 16, pix = p & 65535;
    float x0 = x[(b * 3 + 0) * HW + pix];
    float x1 = x[(b * 3 + 1) * HW + pix];
    float x2 = x[(b * 3 + 2) * HW + pix];
    for (int o = 0; o < C; ++o) {
        float v = bias[o];
        v = fmaf(w[o * 3 + 0], x0, v);
        v = fmaf(w[o * 3 + 1], x1, v);
        v = fmaf(w[o * 3 + 2], x2, v);
        h[(b * C + o) * HW + pix] = v;
    }
}

// ---------------- forward DFT along y ----------------
__global__ __launch_bounds__(256, 2)
void k_fwd_y(const float* __restrict__ h, const float2* __restrict__ tab,
             float2* __restrict__ T1) {
    __shared__ float2 st[256];
    int bc = blockIdx.x;
    int w = threadIdx.x;
    st[w] = tab[w];
    __syncthreads();
    const float* hp = h + bc * HW + w;
    float ar[M], ai[M];
#pragma unroll
    for (int k = 0; k < M; ++k) { ar[k] = 0.f; ai[k] = 0.f; }
    for (int y = 0; y < Hd; ++y) {
        float v = hp[y * Wd];
#pragma unroll
        for (int k = 0; k < M; ++k) {
            float2 e = st[(k * y) & 255];
            ar[k] = fmaf(v, e.x, ar[k]);
            ai[k] = fmaf(v, -e.y, ai[k]);
        }
    }
    float2* out = T1 + bc * (M * Wd) + w;
#pragma unroll
    for (int k = 0; k < M; ++k) out[k * Wd] = make_float2(ar[k], ai[k]);
}

// ---------------- forward DFT along x ----------------
__global__ __launch_bounds__(256, 2)
void k_fwd_x(const float2* __restrict__ T1, const float2* __restrict__ tab,
             float2* __restrict__ X) {
    __shared__ float2 sT[M * Wd];
    __shared__ float2 st[256];
    int bc = blockIdx.x, t = threadIdx.x;
    const float2* src = T1 + bc * (M * Wd);
#pragma unroll
    for (int j = 0; j < M; ++j) sT[j * 256 + t] = src[j * 256 + t];
    st[t] = tab[t];
    __syncthreads();
    int ky = t >> 4, kx = t & 15;
    float xr0 = 0.f, xi0 = 0.f, xr1 = 0.f, xi1 = 0.f;
    for (int w = 0; w < Wd; w += 2) {
        float2 Ta = sT[ky * 256 + w];
        float2 ea = st[(kx * w) & 255];
        xr0 = fmaf(Ta.x, ea.x, fmaf(Ta.y, ea.y, xr0));
        xi0 = fmaf(Ta.y, ea.x, fmaf(-Ta.x, ea.y, xi0));
        float2 Tb = sT[ky * 256 + w + 1];
        float2 eb = st[(kx * (w + 1)) & 255];
        xr1 = fmaf(Tb.x, eb.x, fmaf(Tb.y, eb.y, xr1));
        xi1 = fmaf(Tb.y, eb.x, fmaf(-Tb.x, eb.y, xi1));
    }
    X[bc * 256 + t] = make_float2(xr0 + xr1, xi0 + xi1);
}

// ---------------- mode mixing ----------------
__global__ __launch_bounds__(256, 2)
void k_mix(const float2* __restrict__ X, const float* __restrict__ wre,
           const float* __restrict__ wim, float2* __restrict__ Y) {
    int o = blockIdx.x >> 2;
    int bq = blockIdx.x & 3;
    int m = threadIdx.x;
    int b0 = bq * 2, b1 = bq * 2 + 1;
    float yr0 = 0.f, yi0 = 0.f, yr1 = 0.f, yi1 = 0.f;
    for (int i = 0; i < C; ++i) {
        float wr = wre[(i * C + o) * 256 + m];
        float wi = wim[(i * C + o) * 256 + m];
        float2 x0 = X[(b0 * C + i) * 256 + m];
        float2 x1 = X[(b1 * C + i) * 256 + m];
        yr0 = fmaf(x0.x, wr, fmaf(-x0.y, wi, yr0));
        yi0 = fmaf(x0.x, wi, fmaf(x0.y, wr, yi0));
        yr1 = fmaf(x1.x, wr, fmaf(-x1.y, wi, yr1));
        yi1 = fmaf(x1.x, wi, fmaf(x1.y, wr, yi1));
    }
    Y[(b0 * C + o) * 256 + m] = make_float2(yr0, yi0);
    Y[(b1 * C + o) * 256 + m] = make_float2(yr1, yi1);
}

// ---------------- inverse along y (1/(H*W) and Hermitian x2 folded) ----------------
__global__ __launch_bounds__(256, 2)
void k_inv_y(const float2* __restrict__ Y, const float2* __restrict__ tab,
             float2* __restrict__ G) {
    __shared__ float2 sY[256];
    __shared__ float2 st[256];
    int bc = blockIdx.x, t = threadIdx.x;
    sY[t] = Y[bc * 256 + t];
    st[t] = tab[t];
    __syncthreads();
    float2 out[M];
#pragma unroll
    for (int kx = 0; kx < M; ++kx) {
        float gr = 0.f, gi = 0.f;
#pragma unroll
        for (int ky = 0; ky < M; ++ky) {
            float2 yv = sY[ky * 16 + kx];
            float2 e = st[(ky * t) & 255];
            gr = fmaf(yv.x, e.x, fmaf(-yv.y, e.y, gr));
            gi = fmaf(yv.x, e.y, fmaf(yv.y, e.x, gi));
        }
        float sc = (kx == 0 ? 1.0f : 2.0f) * (1.0f / 65536.0f);
        out[kx] = make_float2(gr * sc, gi * sc);
    }
    float2* gp = G + (bc * 256 + t) * M;
#pragma unroll
    for (int kx = 0; kx < M; ++kx) gp[kx] = out[kx];
}

// ---------------- k_final as augmented GEMM ----------------
// C[o,x] = sum_{k<96} Wq[k][o]*Haug[k][x]; k<64: conv (wwT, h); k>=64: spectral
// (Gq rows = Gr/-Gi, Haug rows = cos/sin planes). 1 wave/block, 64o x 64x tile,
// 8x8 per thread, K in 2 phases of 48 (LDS 24 KB -> 6 blocks/CU). All LDS reads
// span <=256 B/instr (<=2-way, free). R8 lesson: only accumulators may be large;
// no per-thread data arrays (allocator spills them).
__global__ __launch_bounds__(64, 2)
void k_final(float* __restrict__ h, const float* __restrict__ Gq,
             const float* __restrict__ wwT, const float* __restrict__ wb,
             const float* __restrict__ trig) {
    __shared__ float sH[48 * 64];
    __shared__ float sW[48 * 64];
    int blk = blockIdx.x;              // b(8) * y(256) * xq(4)
    int xq = blk & 3, y = (blk >> 2) & 255, b = blk >> 10;
    int x0 = xq * 64;
    int l = threadIdx.x;
    int to = l >> 3, tx = l & 7;
    float acc[8][8];
#pragma unroll
    for (int io = 0; io < 8; ++io) {
        float bv = wb[to * 8 + io];
#pragma unroll
        for (int ix = 0; ix < 8; ++ix) acc[io][ix] = bv;
    }
    float4* sH4 = (float4*)sH;
    float4* sW4 = (float4*)sW;
    for (int ph = 0; ph < 2; ++ph) {
        int kbase = ph * 48;
#pragma unroll
        for (int p = 0; p < 12; ++p) {
            int f = l + p * 64;          // 0..767
            int row = f >> 4, seg = f & 15;
            int kap = kbase + row;
            float4 hv, wv;
            if (kap < 64) {
                hv = *(const float4*)(h + (size_t)(b * 64 + kap) * HW + y * 256 + x0 + seg * 4);
                wv = *(const float4*)(wwT + kap * 64 + seg * 4);
            } else {
                int kk = kap - 64;
                hv = *(const float4*)(trig + kk * 256 + x0 + seg * 4);
                wv = *(const float4*)(Gq + ((size_t)(b * 256 + y) * 32 + kk) * 64 + seg * 4);
            }
            sH4[f] = hv;
            sW4[f] = wv;
        }
        __syncthreads();
#pragma unroll 4
        for (int kk = 0; kk < 48; ++kk) {
            float4 w0 = sW4[kk * 16 + to * 2], w1 = sW4[kk * 16 + to * 2 + 1];
            float4 h0 = sH4[kk * 16 + tx * 2], h1 = sH4[kk * 16 + tx * 2 + 1];
            float aw[8] = {w0.x, w0.y, w0.z, w0.w, w1.x, w1.y, w1.z, w1.w};
            float ah[8] = {h0.x, h0.y, h0.z, h0.w, h1.x, h1.y, h1.z, h1.w};
#pragma unroll
            for (int io = 0; io < 8; ++io)
#pragma unroll
                for (int ix = 0; ix < 8; ++ix)
                    acc[io][ix] = fmaf(aw[io], ah[ix], acc[io][ix]);
        }
        __syncthreads();
    }
#pragma unroll
    for (int io = 0; io < 8; ++io) {
        float* dst = h + (size_t)(b * 64 + to * 8 + io) * HW + y * 256 + x0 + tx * 8;
#pragma unroll
        for (int q = 0; q < 2; ++q) {
            float4 v;
            v.x = fmaxf(acc[io][q * 4 + 0], 0.f);
            v.y = fmaxf(acc[io][q * 4 + 1], 0.f);
            v.z = fmaxf(acc[io][q * 4 + 2], 0.f);
            v.w = fmaxf(acc[io][q * 4 + 3], 0.f);
            *(float4*)(dst + q * 4) = v;
        }
    }
}

// ---------------- fc1+fc2 as GEMM (128m x 64x per block, 8x8/thread) ----------------
__global__ __launch_bounds__(128, 2)
void k_fc12(const float* __restrict__ h, const float* __restrict__ w1T,
            const float* __restrict__ b1, const float* __restrict__ w2,
            const float* __restrict__ b2, float* __restrict__ out) {
    __shared__ float sH[32 * 64];       // 8 KB
    __shared__ float sW[32 * 128];      // 16 KB; reused as part[16][3][64] after GEMM
    int blk = blockIdx.x;               // b(8)*y(256)*xq(4)
    int xq = blk & 3, y = (blk >> 2) & 255, b = blk >> 10;
    int x0 = xq * 64;
    int t = threadIdx.x;
    int tm = t >> 3, tx = t & 7;
    float acc[8][8];
#pragma unroll
    for (int im = 0; im < 8; ++im) {
        float bv = b1[tm * 8 + im];
#pragma unroll
        for (int ix = 0; ix < 8; ++ix) acc[im][ix] = bv;
    }
    float4* sH4 = (float4*)sH;
    float4* sW4 = (float4*)sW;
    for (int ph = 0; ph < 2; ++ph) {
#pragma unroll
        for (int p = 0; p < 4; ++p) {   // sH: 512 float4
            int f = t + p * 128;
            int row = f >> 4, seg = f & 15;
            sH4[f] = *(const float4*)(h + (size_t)(b * 64 + ph * 32 + row) * HW + y * 256 + x0 + seg * 4);
        }
#pragma unroll
        for (int p = 0; p < 8; ++p) {   // sW: 1024 float4
            int f = t + p * 128;
            int row = f >> 5, seg = f & 31;
            sW4[f] = *(const float4*)(w1T + (ph * 32 + row) * 128 + seg * 4);
        }
        __syncthreads();
#pragma unroll 4
        for (int kk = 0; kk < 32; ++kk) {
            float4 w0 = sW4[kk * 32 + tm * 2], w1 = sW4[kk * 32 + tm * 2 + 1];
            float4 h0 = sH4[kk * 16 + tx * 2], h1 = sH4[kk * 16 + tx * 2 + 1];
            float aw[8] = {w0.x, w0.y, w0.z, w0.w, w1.x, w1.y, w1.z, w1.w};
            float ah[8] = {h0.x, h0.y, h0.z, h0.w, h1.x, h1.y, h1.z, h1.w};
#pragma unroll
            for (int im = 0; im < 8; ++im)
#pragma unroll
                for (int ix = 0; ix < 8; ++ix)
                    acc[im][ix] = fmaf(aw[im], ah[ix], acc[im][ix]);
        }
        __syncthreads();
    }
    // relu + fc2 partials: part[tm][j][x] in sW region
    float w2v[3][8];
#pragma unroll
    for (int j = 0; j < 3; ++j)
#pragma unroll
        for (int im = 0; im < 8; ++im) w2v[j][im] = w2[j * NMLP + tm * 8 + im];
#pragma unroll
    for (int im = 0; im < 8; ++im)
#pragma unroll
        for (int ix = 0; ix < 8; ++ix) acc[im][ix] = fmaxf(acc[im][ix], 0.f);
#pragma unroll
    for (int j = 0; j < 3; ++j) {
#pragma unroll
        for (int q = 0; q < 2; ++q) {
            float4 v;
            float s0 = 0.f, s1 = 0.f, s2 = 0.f, s3 = 0.f;
#pragma unroll
            for (int im = 0; im < 8; ++im) {
                s0 = fmaf(w2v[j][im], acc[im][q * 4 + 0], s0);
                s1 = fmaf(w2v[j][im], acc[im][q * 4 + 1], s1);
                s2 = fmaf(w2v[j][im], acc[im][q * 4 + 2], s2);
                s3 = fmaf(w2v[j][im], acc[im][q * 4 + 3], s3);
            }
            v.x = s0; v.y = s1; v.z = s2; v.w = s3;
            sW4[tm * 48 + j * 16 + tx * 2 + q] = v;   // part[tm][j][tx*8+q*4..]
        }
    }
    __syncthreads();
#pragma unroll
    for (int r = 0; r < 2; ++r) {
        int idx = t + r * 128;
        if (idx < 192) {
            int j = idx >> 6, x = idx & 63;
            float s = b2[j];
#pragma unroll
            for (int g = 0; g < 16; ++g) s += sW[g * 192 + j * 64 + x];
            out[(size_t)(b * 3 + j) * HW + y * 256 + x0 + x] = s;
        }
    }
}

extern "C" void kernel_launch(void* const* d_in, const int* in_sizes, int n_in,
                              void* d_out, int out_size, void* d_ws, size_t ws_size,
                              hipStream_t stream) {
    const float* x     = (const float*)d_in[0];
    const float* fc0_w = (const float*)d_in[1];
    const float* fc0_b = (const float*)d_in[2];
    const float* swre  = (const float*)d_in[3];
    const float* swim  = (const float*)d_in[4];
    const float* ww    = (const float*)d_in[5];
    const float* wb    = (const float*)d_in[6];
    const float* fc1w  = (const float*)d_in[7];
    const float* fc1b  = (const float*)d_in[8];
    const float* fc2w  = (const float*)d_in[9];
    const float* fc2b  = (const float*)d_in[10];

    float* ws = (float*)d_ws;
    float2* tab  = (float2*)ws;                       // 512 floats
    float*  h    = ws + 512;                          // 33,554,432
    float2* T1   = (float2*)(ws + 33554944);          // 4,194,304 (doubles as G)
    float2* X    = (float2*)(ws + 37749248);          // 262,144
    float2* Y    = (float2*)(ws + 38011392);          // 262,144
    float*  Gq   = ws + 38273536;                     // 4,194,304
    float*  wwT  = ws + 42467840;                     // 4,096
    float*  w1T  = ws + 42471936;                     // 8,192
    float*  trig = ws + 42480128;                     // 8,192  (total ~170 MB)

    k_table<<<dim3(1), dim3(256), 0, stream>>>(tab);
    k_prep0<<<dim3(96), dim3(256), 0, stream>>>(tab, fc1w, trig, w1T);
    k_fc0<<<dim3(2048), dim3(256), 0, stream>>>(x, fc0_w, fc0_b, h);

    for (int d = 0; d < NDEPTH; ++d) {
        k_fwd_y<<<dim3(512), dim3(256), 0, stream>>>(h, tab, T1);
        k_fwd_x<<<dim3(512), dim3(256), 0, stream>>>(T1, tab, X);
        k_mix<<<dim3(256), dim3(256), 0, stream>>>(X, swre + (size_t)d * C * C * 256,
                                                   swim + (size_t)d * C * C * 256, Y);
        k_inv_y<<<dim3(512), dim3(256), 0, stream>>>(Y, tab, T1 /* = G */);
        k_prep<<<dim3(2064), dim3(256), 0, stream>>>(T1, ww + d * C * C, Gq, wwT);
        k_final<<<dim3(8192), dim3(64), 0, stream>>>(h, Gq, wwT, wb + d * C, trig);
    }
    k_fc12<<<dim3(8192), dim3(128), 0, stream>>>(h, w1T, fc1b, fc2w, fc2b, (float*)d_out);
}

// Round 10
// 1158.683 us; speedup vs baseline: 5.1779x; 1.0372x over previous
//
#include <hip/hip_runtime.h>

#define Hd 256
#define Wd 256
#define HW 65536
#define C 64
#define B 8
#define M 16
#define NDEPTH 4
#define NMLP 128

// ---------------- twiddle table: e^{2*pi*i*t/256}, double-precision accurate --------------
__global__ void k_table(float2* __restrict__ tab) {
    int t = threadIdx.x;
    double a = (6.283185307179586476925286766559 / 256.0) * (double)t;
    tab[t] = make_float2((float)cos(a), (float)sin(a));
}

// ---------------- once: trig planes (32x256) + fc1w^T (64x128) ----------------
__global__ void k_prep0(const float2* __restrict__ tab, const float* __restrict__ fc1w,
                        float* __restrict__ trig, float* __restrict__ w1T) {
    int blk = blockIdx.x, t = threadIdx.x;
    if (blk < 32) {
        int k = blk & 15;
        float2 e = tab[(k * t) & 255];
        trig[blk * 256 + t] = (blk < 16) ? e.x : e.y;
    } else {
        int f = (blk - 32) * 256 + t;    // 0..16383
        int i = f >> 7, m = f & 127;
        w1T[i * 128 + m] = fc1w[m * 64 + i];
    }
}

// ---------------- per layer: ww^T (64x64) + Gq[b,y][kk][o] (2048x32x64) ----------------
__global__ void k_prep(const float2* __restrict__ G, const float* __restrict__ ww,
                       float* __restrict__ Gq, float* __restrict__ wwT) {
    int blk = blockIdx.x, t = threadIdx.x;
    if (blk < 2048) {
        int b = blk >> 8, y = blk & 255;
#pragma unroll
        for (int p = 0; p < 8; ++p) {
            int f = t + p * 256;           // 0..2047
            int kk = f >> 6, o = f & 63;
            float2 g = G[((size_t)(b * 64 + o) * 256 + y) * 16 + (kk & 15)];
            Gq[((size_t)(b * 256 + y) * 32 + kk) * 64 + o] = (kk < 16) ? g.x : -g.y;
        }
    } else {
        int f = (blk - 2048) * 256 + t;    // 0..4095
        int i = f >> 6, o = f & 63;
        wwT[i * 64 + o] = ww[o * 64 + i];
    }
}

// ---------------- fc0: 3 -> 64 channels, per pixel ----------------
__global__ void k_fc0(const float* __restrict__ x, const float* __restrict__ w,
                      const float* __restrict__ bias, float* __restrict__ h) {
    int p = blockIdx.x * 256 + threadIdx.x;
    int b = p >> 16, pix = p & 65535;
    float x0 = x[(b * 3 + 0) * HW + pix];
    float x1 = x[(b * 3 + 1) * HW + pix];
    float x2 = x[(b * 3 + 2) * HW + pix];
    for (int o = 0; o < C; ++o) {
        float v = bias[o];
        v = fmaf(w[o * 3 + 0], x0, v);
        v = fmaf(w[o * 3 + 1], x1, v);
        v = fmaf(w[o * 3 + 2], x2, v);
        h[(b * C + o) * HW + pix] = v;
    }
}

// ---------------- forward DFT along y ----------------
__global__ __launch_bounds__(256, 2)
void k_fwd_y(const float* __restrict__ h, const float2* __restrict__ tab,
             float2* __restrict__ T1) {
    __shared__ float2 st[256];
    int bc = blockIdx.x;
    int w = threadIdx.x;
    st[w] = tab[w];
    __syncthreads();
    const float* hp = h + bc * HW + w;
    float ar[M], ai[M];
#pragma unroll
    for (int k = 0; k < M; ++k) { ar[k] = 0.f; ai[k] = 0.f; }
    for (int y = 0; y < Hd; ++y) {
        float v = hp[y * Wd];
#pragma unroll
        for (int k = 0; k < M; ++k) {
            float2 e = st[(k * y) & 255];
            ar[k] = fmaf(v, e.x, ar[k]);
            ai[k] = fmaf(v, -e.y, ai[k]);
        }
    }
    float2* out = T1 + bc * (M * Wd) + w;
#pragma unroll
    for (int k = 0; k < M; ++k) out[k * Wd] = make_float2(ar[k], ai[k]);
}

// ---------------- forward DFT along x ----------------
__global__ __launch_bounds__(256, 2)
void k_fwd_x(const float2* __restrict__ T1, const float2* __restrict__ tab,
             float2* __restrict__ X) {
    __shared__ float2 sT[M * Wd];
    __shared__ float2 st[256];
    int bc = blockIdx.x, t = threadIdx.x;
    const float2* src = T1 + bc * (M * Wd);
#pragma unroll
    for (int j = 0; j < M; ++j) sT[j * 256 + t] = src[j * 256 + t];
    st[t] = tab[t];
    __syncthreads();
    int ky = t >> 4, kx = t & 15;
    float xr0 = 0.f, xi0 = 0.f, xr1 = 0.f, xi1 = 0.f;
    for (int w = 0; w < Wd; w += 2) {
        float2 Ta = sT[ky * 256 + w];
        float2 ea = st[(kx * w) & 255];
        xr0 = fmaf(Ta.x, ea.x, fmaf(Ta.y, ea.y, xr0));
        xi0 = fmaf(Ta.y, ea.x, fmaf(-Ta.x, ea.y, xi0));
        float2 Tb = sT[ky * 256 + w + 1];
        float2 eb = st[(kx * (w + 1)) & 255];
        xr1 = fmaf(Tb.x, eb.x, fmaf(Tb.y, eb.y, xr1));
        xi1 = fmaf(Tb.y, eb.x, fmaf(-Tb.x, eb.y, xi1));
    }
    X[bc * 256 + t] = make_float2(xr0 + xr1, xi0 + xi1);
}

// ---------------- mode mixing ----------------
__global__ __launch_bounds__(256, 2)
void k_mix(const float2* __restrict__ X, const float* __restrict__ wre,
           const float* __restrict__ wim, float2* __restrict__ Y) {
    int o = blockIdx.x >> 2;
    int bq = blockIdx.x & 3;
    int m = threadIdx.x;
    int b0 = bq * 2, b1 = bq * 2 + 1;
    float yr0 = 0.f, yi0 = 0.f, yr1 = 0.f, yi1 = 0.f;
    for (int i = 0; i < C; ++i) {
        float wr = wre[(i * C + o) * 256 + m];
        float wi = wim[(i * C + o) * 256 + m];
        float2 x0 = X[(b0 * C + i) * 256 + m];
        float2 x1 = X[(b1 * C + i) * 256 + m];
        yr0 = fmaf(x0.x, wr, fmaf(-x0.y, wi, yr0));
        yi0 = fmaf(x0.x, wi, fmaf(x0.y, wr, yi0));
        yr1 = fmaf(x1.x, wr, fmaf(-x1.y, wi, yr1));
        yi1 = fmaf(x1.x, wi, fmaf(x1.y, wr, yi1));
    }
    Y[(b0 * C + o) * 256 + m] = make_float2(yr0, yi0);
    Y[(b1 * C + o) * 256 + m] = make_float2(yr1, yi1);
}

// ---------------- inverse along y (1/(H*W) and Hermitian x2 folded) ----------------
__global__ __launch_bounds__(256, 2)
void k_inv_y(const float2* __restrict__ Y, const float2* __restrict__ tab,
             float2* __restrict__ G) {
    __shared__ float2 sY[256];
    __shared__ float2 st[256];
    int bc = blockIdx.x, t = threadIdx.x;
    sY[t] = Y[bc * 256 + t];
    st[t] = tab[t];
    __syncthreads();
    float2 out[M];
#pragma unroll
    for (int kx = 0; kx < M; ++kx) {
        float gr = 0.f, gi = 0.f;
#pragma unroll
        for (int ky = 0; ky < M; ++ky) {
            float2 yv = sY[ky * 16 + kx];
            float2 e = st[(ky * t) & 255];
            gr = fmaf(yv.x, e.x, fmaf(-yv.y, e.y, gr));
            gi = fmaf(yv.x, e.y, fmaf(yv.y, e.x, gi));
        }
        float sc = (kx == 0 ? 1.0f : 2.0f) * (1.0f / 65536.0f);
        out[kx] = make_float2(gr * sc, gi * sc);
    }
    float2* gp = G + (bc * 256 + t) * M;
#pragma unroll
    for (int kx = 0; kx < M; ++kx) gp[kx] = out[kx];
}

// ---------------- k_final as augmented GEMM ----------------
// C[o,x] = sum_{k<96} Wq[k][o]*Haug[k][x]; k<64: conv (wwT, h); k>=64: spectral
// (Gq rows, trig planes). R9: 64-thread blocks hit 1.1 waves/SIMD (Occupancy 14%,
// VALUBusy 46%) — LDS latency + barrier drains fully exposed. R10: 256-thread
// blocks, 64o x 256x tile, K=96 in 3 phases of 32 (sH 32KB + sW 8KB = 40KB ->
// 4 blocks/CU = 16 waves/CU = 4/SIMD). Per-acc K order unchanged (absmax margin
// is 1.23x — do not deepen chains). (256,2): cap 256 VGPRs; R8 lesson — never
// force high waves/EU, the allocator squeezes to 64 and spills.
__global__ __launch_bounds__(256, 2)
void k_final(float* __restrict__ h, const float* __restrict__ Gq,
             const float* __restrict__ wwT, const float* __restrict__ wb,
             const float* __restrict__ trig) {
    __shared__ float sH[32 * 256];     // 32 KB
    __shared__ float sW[32 * 64];      // 8 KB
    int blk = blockIdx.x;              // b(8) * y(256)
    int y = blk & 255, b = blk >> 8;
    int t = threadIdx.x;
    int to = t >> 5, tx = t & 31;      // o-tile row group (8 o's), x group (8 x's)
    float acc[8][8];
#pragma unroll
    for (int io = 0; io < 8; ++io) {
        float bv = wb[to * 8 + io];
#pragma unroll
        for (int ix = 0; ix < 8; ++ix) acc[io][ix] = bv;
    }
    float4* sH4 = (float4*)sH;
    float4* sW4 = (float4*)sW;
    for (int ph = 0; ph < 3; ++ph) {
        int kbase = ph * 32;
        if (ph < 2) {
            // conv rows: sH <- h[b, kbase..kbase+31, y, 0..255]; sW <- wwT rows
#pragma unroll
            for (int p = 0; p < 8; ++p) {      // 2048 float4
                int f = t + p * 256;
                int row = f >> 6, seg = f & 63;
                sH4[f] = *(const float4*)(h + (size_t)(b * 64 + kbase + row) * HW + y * 256 + seg * 4);
            }
#pragma unroll
            for (int p = 0; p < 2; ++p) {      // 512 float4
                int f = t + p * 256;
                int row = f >> 4, seg = f & 15;
                sW4[f] = *(const float4*)(wwT + (kbase + row) * 64 + seg * 4);
            }
        } else {
            // spectral rows: sH <- trig planes; sW <- Gq[b,y] rows
#pragma unroll
            for (int p = 0; p < 8; ++p) {
                int f = t + p * 256;
                int row = f >> 6, seg = f & 63;
                sH4[f] = *(const float4*)(trig + row * 256 + seg * 4);
            }
#pragma unroll
            for (int p = 0; p < 2; ++p) {
                int f = t + p * 256;
                int row = f >> 4, seg = f & 15;
                sW4[f] = *(const float4*)(Gq + ((size_t)(b * 256 + y) * 32 + row) * 64 + seg * 4);
            }
        }
        __syncthreads();
#pragma unroll 4
        for (int kk = 0; kk < 32; ++kk) {
            float4 w0 = sW4[kk * 16 + to * 2], w1 = sW4[kk * 16 + to * 2 + 1];
            float4 h0 = sH4[kk * 64 + tx * 2], h1 = sH4[kk * 64 + tx * 2 + 1];
            float aw[8] = {w0.x, w0.y, w0.z, w0.w, w1.x, w1.y, w1.z, w1.w};
            float ah[8] = {h0.x, h0.y, h0.z, h0.w, h1.x, h1.y, h1.z, h1.w};
#pragma unroll
            for (int io = 0; io < 8; ++io)
#pragma unroll
                for (int ix = 0; ix < 8; ++ix)
                    acc[io][ix] = fmaf(aw[io], ah[ix], acc[io][ix]);
        }
        __syncthreads();
    }
#pragma unroll
    for (int io = 0; io < 8; ++io) {
        float* dst = h + (size_t)(b * 64 + to * 8 + io) * HW + y * 256 + tx * 8;
#pragma unroll
        for (int q = 0; q < 2; ++q) {
            float4 v;
            v.x = fmaxf(acc[io][q * 4 + 0], 0.f);
            v.y = fmaxf(acc[io][q * 4 + 1], 0.f);
            v.z = fmaxf(acc[io][q * 4 + 2], 0.f);
            v.w = fmaxf(acc[io][q * 4 + 3], 0.f);
            *(float4*)(dst + q * 4) = v;
        }
    }
}

// ---------------- fc1+fc2 as GEMM (128m x 64x per block, 8x8/thread) ----------------
__global__ __launch_bounds__(128, 2)
void k_fc12(const float* __restrict__ h, const float* __restrict__ w1T,
            const float* __restrict__ b1, const float* __restrict__ w2,
            const float* __restrict__ b2, float* __restrict__ out) {
    __shared__ float sH[32 * 64];       // 8 KB
    __shared__ float sW[32 * 128];      // 16 KB; reused as part[16][3][64] after GEMM
    int blk = blockIdx.x;               // b(8)*y(256)*xq(4)
    int xq = blk & 3, y = (blk >> 2) & 255, b = blk >> 10;
    int x0 = xq * 64;
    int t = threadIdx.x;
    int tm = t >> 3, tx = t & 7;
    float acc[8][8];
#pragma unroll
    for (int im = 0; im < 8; ++im) {
        float bv = b1[tm * 8 + im];
#pragma unroll
        for (int ix = 0; ix < 8; ++ix) acc[im][ix] = bv;
    }
    float4* sH4 = (float4*)sH;
    float4* sW4 = (float4*)sW;
    for (int ph = 0; ph < 2; ++ph) {
#pragma unroll
        for (int p = 0; p < 4; ++p) {   // sH: 512 float4
            int f = t + p * 128;
            int row = f >> 4, seg = f & 15;
            sH4[f] = *(const float4*)(h + (size_t)(b * 64 + ph * 32 + row) * HW + y * 256 + x0 + seg * 4);
        }
#pragma unroll
        for (int p = 0; p < 8; ++p) {   // sW: 1024 float4
            int f = t + p * 128;
            int row = f >> 5, seg = f & 31;
            sW4[f] = *(const float4*)(w1T + (ph * 32 + row) * 128 + seg * 4);
        }
        __syncthreads();
#pragma unroll 4
        for (int kk = 0; kk < 32; ++kk) {
            float4 w0 = sW4[kk * 32 + tm * 2], w1 = sW4[kk * 32 + tm * 2 + 1];
            float4 h0 = sH4[kk * 16 + tx * 2], h1 = sH4[kk * 16 + tx * 2 + 1];
            float aw[8] = {w0.x, w0.y, w0.z, w0.w, w1.x, w1.y, w1.z, w1.w};
            float ah[8] = {h0.x, h0.y, h0.z, h0.w, h1.x, h1.y, h1.z, h1.w};
#pragma unroll
            for (int im = 0; im < 8; ++im)
#pragma unroll
                for (int ix = 0; ix < 8; ++ix)
                    acc[im][ix] = fmaf(aw[im], ah[ix], acc[im][ix]);
        }
        __syncthreads();
    }
    float w2v[3][8];
#pragma unroll
    for (int j = 0; j < 3; ++j)
#pragma unroll
        for (int im = 0; im < 8; ++im) w2v[j][im] = w2[j * NMLP + tm * 8 + im];
#pragma unroll
    for (int im = 0; im < 8; ++im)
#pragma unroll
        for (int ix = 0; ix < 8; ++ix) acc[im][ix] = fmaxf(acc[im][ix], 0.f);
#pragma unroll
    for (int j = 0; j < 3; ++j) {
#pragma unroll
        for (int q = 0; q < 2; ++q) {
            float4 v;
            float s0 = 0.f, s1 = 0.f, s2 = 0.f, s3 = 0.f;
#pragma unroll
            for (int im = 0; im < 8; ++im) {
                s0 = fmaf(w2v[j][im], acc[im][q * 4 + 0], s0);
                s1 = fmaf(w2v[j][im], acc[im][q * 4 + 1], s1);
                s2 = fmaf(w2v[j][im], acc[im][q * 4 + 2], s2);
                s3 = fmaf(w2v[j][im], acc[im][q * 4 + 3], s3);
            }
            v.x = s0; v.y = s1; v.z = s2; v.w = s3;
            sW4[tm * 48 + j * 16 + tx * 2 + q] = v;
        }
    }
    __syncthreads();
#pragma unroll
    for (int r = 0; r < 2; ++r) {
        int idx = t + r * 128;
        if (idx < 192) {
            int j = idx >> 6, x = idx & 63;
            float s = b2[j];
#pragma unroll
            for (int g = 0; g < 16; ++g) s += sW[g * 192 + j * 64 + x];
            out[(size_t)(b * 3 + j) * HW + y * 256 + x0 + x] = s;
        }
    }
}

extern "C" void kernel_launch(void* const* d_in, const int* in_sizes, int n_in,
                              void* d_out, int out_size, void* d_ws, size_t ws_size,
                              hipStream_t stream) {
    const float* x     = (const float*)d_in[0];
    const float* fc0_w = (const float*)d_in[1];
    const float* fc0_b = (const float*)d_in[2];
    const float* swre  = (const float*)d_in[3];
    const float* swim  = (const float*)d_in[4];
    const float* ww    = (const float*)d_in[5];
    const float* wb    = (const float*)d_in[6];
    const float* fc1w  = (const float*)d_in[7];
    const float* fc1b  = (const float*)d_in[8];
    const float* fc2w  = (const float*)d_in[9];
    const float* fc2b  = (const float*)d_in[10];

    float* ws = (float*)d_ws;
    float2* tab  = (float2*)ws;                       // 512 floats
    float*  h    = ws + 512;                          // 33,554,432
    float2* T1   = (float2*)(ws + 33554944);          // 4,194,304 (doubles as G)
    float2* X    = (float2*)(ws + 37749248);          // 262,144
    float2* Y    = (float2*)(ws + 38011392);          // 262,144
    float*  Gq   = ws + 38273536;                     // 4,194,304
    float*  wwT  = ws + 42467840;                     // 4,096
    float*  w1T  = ws + 42471936;                     // 8,192
    float*  trig = ws + 42480128;                     // 8,192

    k_table<<<dim3(1), dim3(256), 0, stream>>>(tab);
    k_prep0<<<dim3(96), dim3(256), 0, stream>>>(tab, fc1w, trig, w1T);
    k_fc0<<<dim3(2048), dim3(256), 0, stream>>>(x, fc0_w, fc0_b, h);

    for (int d = 0; d < NDEPTH; ++d) {
        k_fwd_y<<<dim3(512), dim3(256), 0, stream>>>(h, tab, T1);
        k_fwd_x<<<dim3(512), dim3(256), 0, stream>>>(T1, tab, X);
        k_mix<<<dim3(256), dim3(256), 0, stream>>>(X, swre + (size_t)d * C * C * 256,
                                                   swim + (size_t)d * C * C * 256, Y);
        k_inv_y<<<dim3(512), dim3(256), 0, stream>>>(Y, tab, T1 /* = G */);
        k_prep<<<dim3(2064), dim3(256), 0, stream>>>(T1, ww + d * C * C, Gq, wwT);
        k_final<<<dim3(2048), dim3(256), 0, stream>>>(h, Gq, wwT, wb + d * C, trig);
    }
    k_fc12<<<dim3(8192), dim3(128), 0, stream>>>(h, w1T, fc1b, fc2w, fc2b, (float*)d_out);
}

// Round 11
// 939.691 us; speedup vs baseline: 6.3846x; 1.2330x over previous
//
#include <hip/hip_runtime.h>

#define Hd 256
#define Wd 256
#define HW 65536
#define C 64
#define B 8
#define M 16
#define NDEPTH 4
#define NMLP 128

// ---------------- twiddle table: e^{2*pi*i*t/256}, double-precision accurate --------------
__global__ void k_table(float2* __restrict__ tab) {
    int t = threadIdx.x;
    double a = (6.283185307179586476925286766559 / 256.0) * (double)t;
    tab[t] = make_float2((float)cos(a), (float)sin(a));
}

// ---------------- once: trig (k_final), trigFT (fwd_y), w1T, wwT_all ----------------
// R11 fix: old version launched 64 blocks for the 8192-float w1T copy -> blocks 64..95
// wrote OOB into trig (passed only by dispatch-order luck). Ranges now exact.
__global__ void k_prep0(const float2* __restrict__ tab, const float* __restrict__ fc1w,
                        const float* __restrict__ ww,
                        float* __restrict__ trig, float* __restrict__ trigFT,
                        float* __restrict__ w1T, float* __restrict__ wwT_all) {
    int blk = blockIdx.x, t = threadIdx.x;
    if (blk < 32) {                    // trig[kk][x]: cos for kk<16, +sin for kk>=16
        int k = blk & 15;
        float2 e = tab[(k * t) & 255];
        trig[blk * 256 + t] = (blk < 16) ? e.x : e.y;
    } else if (blk < 64) {             // trigFT[y][kk]: cos for kk<16, -sin for kk>=16
        int f = (blk - 32) * 256 + t;  // 0..8191
        int y = f >> 5, kk = f & 31;
        float2 e = tab[((kk & 15) * y) & 255];
        trigFT[f] = (kk < 16) ? e.x : -e.y;
    } else if (blk < 96) {             // w1T[i][m] = fc1w[m][i]
        int f = (blk - 64) * 256 + t;  // 0..8191
        int i = f >> 7, m = f & 127;
        w1T[f] = fc1w[m * 64 + i];
    } else {                           // wwT_all[d][i][o] = ww[d][o][i]
        int f = (blk - 96) * 256 + t;  // 0..16383
        int d = f >> 12, r = f & 4095;
        int i = r >> 6, o = r & 63;
        wwT_all[f] = ww[d * 4096 + o * 64 + i];
    }
}

// ---------------- fc0: 3 -> 64 channels, per pixel ----------------
__global__ void k_fc0(const float* __restrict__ x, const float* __restrict__ w,
                      const float* __restrict__ bias, float* __restrict__ h) {
    int p = blockIdx.x * 256 + threadIdx.x;
    int b = p >> 16, pix = p & 65535;
    float x0 = x[(b * 3 + 0) * HW + pix];
    float x1 = x[(b * 3 + 1) * HW + pix];
    float x2 = x[(b * 3 + 2) * HW + pix];
    for (int o = 0; o < C; ++o) {
        float v = bias[o];
        v = fmaf(w[o * 3 + 0], x0, v);
        v = fmaf(w[o * 3 + 1], x1, v);
        v = fmaf(w[o * 3 + 2], x2, v);
        h[(b * C + o) * HW + pix] = v;
    }
}

// ---------------- forward y-DFT as GEMM: T1F[bc][r][w] = sum_y trigF[r][y] h[bc][y][w] ----
// r<16: Re rows (cos), r>=16: Im rows (-sin already folded in trigFT). R9/R10 recipe:
// 8x8 register tile, only accumulators large. Same sequential-y order as the old
// kernel -> absmax unchanged.
__global__ __launch_bounds__(128, 2)
void k_fwd_y(const float* __restrict__ h, const float* __restrict__ trigFT,
             float* __restrict__ T1F) {
    __shared__ float sH[32 * 256];   // 32 KB
    __shared__ float sE[32 * 32];    // 4 KB, [y][kk]
    int bc = blockIdx.x, t = threadIdx.x;
    int rg = t >> 5, cg = t & 31;    // 4 row-groups (8 rows), 32 col-groups (8 cols)
    float acc[8][8];
#pragma unroll
    for (int io = 0; io < 8; ++io)
#pragma unroll
        for (int ix = 0; ix < 8; ++ix) acc[io][ix] = 0.f;
    float4* sH4 = (float4*)sH;
    float4* sE4 = (float4*)sE;
    for (int ph = 0; ph < 8; ++ph) {
#pragma unroll
        for (int p = 0; p < 16; ++p) {     // 2048 float4, coalesced
            int f = t + p * 128;
            sH4[f] = *(const float4*)(h + (size_t)bc * HW + ph * 32 * 256 + f * 4);
        }
#pragma unroll
        for (int p = 0; p < 2; ++p) {      // 256 float4
            int f = t + p * 128;
            sE4[f] = *(const float4*)(trigFT + ph * 1024 + f * 4);
        }
        __syncthreads();
#pragma unroll 4
        for (int yy = 0; yy < 32; ++yy) {
            float4 e0 = sE4[yy * 8 + rg * 2], e1 = sE4[yy * 8 + rg * 2 + 1];
            float4 h0 = sH4[yy * 64 + cg * 2], h1 = sH4[yy * 64 + cg * 2 + 1];
            float ae[8] = {e0.x, e0.y, e0.z, e0.w, e1.x, e1.y, e1.z, e1.w};
            float ah[8] = {h0.x, h0.y, h0.z, h0.w, h1.x, h1.y, h1.z, h1.w};
#pragma unroll
            for (int io = 0; io < 8; ++io)
#pragma unroll
                for (int ix = 0; ix < 8; ++ix)
                    acc[io][ix] = fmaf(ae[io], ah[ix], acc[io][ix]);
        }
        __syncthreads();
    }
#pragma unroll
    for (int io = 0; io < 8; ++io) {
        float* dst = T1F + (size_t)bc * 8192 + (rg * 8 + io) * 256 + cg * 8;
#pragma unroll
        for (int q = 0; q < 2; ++q) {
            float4 v;
            v.x = acc[io][q * 4 + 0]; v.y = acc[io][q * 4 + 1];
            v.z = acc[io][q * 4 + 2]; v.w = acc[io][q * 4 + 3];
            *(float4*)(dst + q * 4) = v;
        }
    }
}

// ---------------- forward x-DFT: X[bc,ky*16+kx] from planar T1F ----------------
// sT padded to stride 260 (4 distinct ky addresses land on 4 distinct banks).
__global__ __launch_bounds__(256, 2)
void k_fwd_x(const float* __restrict__ T1F, const float2* __restrict__ tab,
             float2* __restrict__ X) {
    __shared__ float sT[32 * 260];   // 33.3 KB
    __shared__ float2 st[256];
    int bc = blockIdx.x, t = threadIdx.x;
#pragma unroll
    for (int p = 0; p < 8; ++p) {    // 2048 float4
        int f = t + p * 256;
        int row = f >> 6, seg = f & 63;
        ((float4*)(sT + row * 260))[seg] = *(const float4*)(T1F + (size_t)bc * 8192 + f * 4);
    }
    st[t] = tab[t];
    __syncthreads();
    int ky = t >> 4, kx = t & 15;
    const float* Tr = sT + ky * 260;
    const float* Ti = sT + (16 + ky) * 260;
    float xr0 = 0.f, xi0 = 0.f, xr1 = 0.f, xi1 = 0.f;
    for (int w = 0; w < Wd; w += 2) {
        float tra = Tr[w], tia = Ti[w];
        float2 ea = st[(kx * w) & 255];
        xr0 = fmaf(tra, ea.x, fmaf(tia, ea.y, xr0));
        xi0 = fmaf(tia, ea.x, fmaf(-tra, ea.y, xi0));
        float trb = Tr[w + 1], tib = Ti[w + 1];
        float2 eb = st[(kx * (w + 1)) & 255];
        xr1 = fmaf(trb, eb.x, fmaf(tib, eb.y, xr1));
        xi1 = fmaf(tib, eb.x, fmaf(-trb, eb.y, xi1));
    }
    X[bc * 256 + t] = make_float2(xr0 + xr1, xi0 + xi1);
}

// ---------------- mode mixing ----------------
__global__ __launch_bounds__(256, 2)
void k_mix(const float2* __restrict__ X, const float* __restrict__ wre,
           const float* __restrict__ wim, float2* __restrict__ Y) {
    int o = blockIdx.x >> 2;
    int bq = blockIdx.x & 3;
    int m = threadIdx.x;
    int b0 = bq * 2, b1 = bq * 2 + 1;
    float yr0 = 0.f, yi0 = 0.f, yr1 = 0.f, yi1 = 0.f;
    for (int i = 0; i < C; ++i) {
        float wr = wre[(i * C + o) * 256 + m];
        float wi = wim[(i * C + o) * 256 + m];
        float2 x0 = X[(b0 * C + i) * 256 + m];
        float2 x1 = X[(b1 * C + i) * 256 + m];
        yr0 = fmaf(x0.x, wr, fmaf(-x0.y, wi, yr0));
        yi0 = fmaf(x0.x, wi, fmaf(x0.y, wr, yi0));
        yr1 = fmaf(x1.x, wr, fmaf(-x1.y, wi, yr1));
        yi1 = fmaf(x1.x, wi, fmaf(x1.y, wr, yi1));
    }
    Y[(b0 * C + o) * 256 + m] = make_float2(yr0, yi0);
    Y[(b1 * C + o) * 256 + m] = make_float2(yr1, yi1);
}

// ---------------- fused inverse-y + Gq production (replaces k_inv_y + k_prep) ------------
// Key: Y[b,o,ky*16+kx] is y-independent -> hold 16 (Yr,Yi) scaled in regs (32 regs,
// under the spill trigger), emit Gq rows kx (Re) and 16+kx (-Im) for a 16-y tile with
// o-coalesced writes. No G round-trip, no strided re-read (old k_prep had 32 KB lane
// stride = 8x fetch amplification).
__global__ __launch_bounds__(256, 2)
void k_invy(const float2* __restrict__ Y, const float2* __restrict__ tab,
            float* __restrict__ Gq) {
    __shared__ float2 st[256];
    int blk = blockIdx.x;              // 8b x 4pg x 16yt
    int yt = blk & 15, pg = (blk >> 4) & 3, b = blk >> 6;
    int t = threadIdx.x;
    st[t] = tab[t];
    int o = t & 63, kx = pg * 4 + (t >> 6);
    __syncthreads();
    float sc = (kx == 0 ? 1.0f : 2.0f) * (1.0f / 65536.0f);
    float yr[16], yi[16];
    const float2* yp = Y + (size_t)(b * 64 + o) * 256 + kx;
#pragma unroll
    for (int ky = 0; ky < 16; ++ky) {
        float2 v = yp[ky * 16];
        yr[ky] = v.x * sc;
        yi[ky] = v.y * sc;
    }
    int y0 = yt * 16;
    for (int yy = 0; yy < 16; ++yy) {
        int y = y0 + yy;
        float re = 0.f, im = 0.f;
#pragma unroll
        for (int ky = 0; ky < 16; ++ky) {
            float2 e = st[(ky * y) & 255];   // wave-uniform broadcast
            re = fmaf(yr[ky], e.x, re);
            re = fmaf(-yi[ky], e.y, re);
            im = fmaf(yr[ky], e.y, im);
            im = fmaf(yi[ky], e.x, im);
        }
        float* gp = Gq + (size_t)(b * 256 + y) * 32 * 64 + o;
        gp[kx * 64] = re;                    // row kk = kx  (Re)
        gp[(16 + kx) * 64] = -im;            // row kk = 16+kx (-Im)
    }
}

// ---------------- k_final as augmented GEMM (R10 structure, unchanged) ----------------
__global__ __launch_bounds__(256, 2)
void k_final(float* __restrict__ h, const float* __restrict__ Gq,
             const float* __restrict__ wwT, const float* __restrict__ wb,
             const float* __restrict__ trig) {
    __shared__ float sH[32 * 256];     // 32 KB
    __shared__ float sW[32 * 64];      // 8 KB
    int blk = blockIdx.x;              // b(8) * y(256)
    int y = blk & 255, b = blk >> 8;
    int t = threadIdx.x;
    int to = t >> 5, tx = t & 31;
    float acc[8][8];
#pragma unroll
    for (int io = 0; io < 8; ++io) {
        float bv = wb[to * 8 + io];
#pragma unroll
        for (int ix = 0; ix < 8; ++ix) acc[io][ix] = bv;
    }
    float4* sH4 = (float4*)sH;
    float4* sW4 = (float4*)sW;
    for (int ph = 0; ph < 3; ++ph) {
        int kbase = ph * 32;
        if (ph < 2) {
#pragma unroll
            for (int p = 0; p < 8; ++p) {
                int f = t + p * 256;
                int row = f >> 6, seg = f & 63;
                sH4[f] = *(const float4*)(h + (size_t)(b * 64 + kbase + row) * HW + y * 256 + seg * 4);
            }
#pragma unroll
            for (int p = 0; p < 2; ++p) {
                int f = t + p * 256;
                int row = f >> 4, seg = f & 15;
                sW4[f] = *(const float4*)(wwT + (kbase + row) * 64 + seg * 4);
            }
        } else {
#pragma unroll
            for (int p = 0; p < 8; ++p) {
                int f = t + p * 256;
                int row = f >> 6, seg = f & 63;
                sH4[f] = *(const float4*)(trig + row * 256 + seg * 4);
            }
#pragma unroll
            for (int p = 0; p < 2; ++p) {
                int f = t + p * 256;
                int row = f >> 4, seg = f & 15;
                sW4[f] = *(const float4*)(Gq + ((size_t)(b * 256 + y) * 32 + row) * 64 + seg * 4);
            }
        }
        __syncthreads();
#pragma unroll 4
        for (int kk = 0; kk < 32; ++kk) {
            float4 w0 = sW4[kk * 16 + to * 2], w1 = sW4[kk * 16 + to * 2 + 1];
            float4 h0 = sH4[kk * 64 + tx * 2], h1 = sH4[kk * 64 + tx * 2 + 1];
            float aw[8] = {w0.x, w0.y, w0.z, w0.w, w1.x, w1.y, w1.z, w1.w};
            float ah[8] = {h0.x, h0.y, h0.z, h0.w, h1.x, h1.y, h1.z, h1.w};
#pragma unroll
            for (int io = 0; io < 8; ++io)
#pragma unroll
                for (int ix = 0; ix < 8; ++ix)
                    acc[io][ix] = fmaf(aw[io], ah[ix], acc[io][ix]);
        }
        __syncthreads();
    }
#pragma unroll
    for (int io = 0; io < 8; ++io) {
        float* dst = h + (size_t)(b * 64 + to * 8 + io) * HW + y * 256 + tx * 8;
#pragma unroll
        for (int q = 0; q < 2; ++q) {
            float4 v;
            v.x = fmaxf(acc[io][q * 4 + 0], 0.f);
            v.y = fmaxf(acc[io][q * 4 + 1], 0.f);
            v.z = fmaxf(acc[io][q * 4 + 2], 0.f);
            v.w = fmaxf(acc[io][q * 4 + 3], 0.f);
            *(float4*)(dst + q * 4) = v;
        }
    }
}

// ---------------- fc1+fc2 as GEMM (unchanged from R10) ----------------
__global__ __launch_bounds__(128, 2)
void k_fc12(const float* __restrict__ h, const float* __restrict__ w1T,
            const float* __restrict__ b1, const float* __restrict__ w2,
            const float* __restrict__ b2, float* __restrict__ out) {
    __shared__ float sH[32 * 64];       // 8 KB
    __shared__ float sW[32 * 128];      // 16 KB; reused as part[16][3][64]
    int blk = blockIdx.x;               // b(8)*y(256)*xq(4)
    int xq = blk & 3, y = (blk >> 2) & 255, b = blk >> 10;
    int x0 = xq * 64;
    int t = threadIdx.x;
    int tm = t >> 3, tx = t & 7;
    float acc[8][8];
#pragma unroll
    for (int im = 0; im < 8; ++im) {
        float bv = b1[tm * 8 + im];
#pragma unroll
        for (int ix = 0; ix < 8; ++ix) acc[im][ix] = bv;
    }
    float4* sH4 = (float4*)sH;
    float4* sW4 = (float4*)sW;
    for (int ph = 0; ph < 2; ++ph) {
#pragma unroll
        for (int p = 0; p < 4; ++p) {
            int f = t + p * 128;
            int row = f >> 4, seg = f & 15;
            sH4[f] = *(const float4*)(h + (size_t)(b * 64 + ph * 32 + row) * HW + y * 256 + x0 + seg * 4);
        }
#pragma unroll
        for (int p = 0; p < 8; ++p) {
            int f = t + p * 128;
            int row = f >> 5, seg = f & 31;
            sW4[f] = *(const float4*)(w1T + (ph * 32 + row) * 128 + seg * 4);
        }
        __syncthreads();
#pragma unroll 4
        for (int kk = 0; kk < 32; ++kk) {
            float4 w0 = sW4[kk * 32 + tm * 2], w1 = sW4[kk * 32 + tm * 2 + 1];
            float4 h0 = sH4[kk * 16 + tx * 2], h1 = sH4[kk * 16 + tx * 2 + 1];
            float aw[8] = {w0.x, w0.y, w0.z, w0.w, w1.x, w1.y, w1.z, w1.w};
            float ah[8] = {h0.x, h0.y, h0.z, h0.w, h1.x, h1.y, h1.z, h1.w};
#pragma unroll
            for (int im = 0; im < 8; ++im)
#pragma unroll
                for (int ix = 0; ix < 8; ++ix)
                    acc[im][ix] = fmaf(aw[im], ah[ix], acc[im][ix]);
        }
        __syncthreads();
    }
    float w2v[3][8];
#pragma unroll
    for (int j = 0; j < 3; ++j)
#pragma unroll
        for (int im = 0; im < 8; ++im) w2v[j][im] = w2[j * NMLP + tm * 8 + im];
#pragma unroll
    for (int im = 0; im < 8; ++im)
#pragma unroll
        for (int ix = 0; ix < 8; ++ix) acc[im][ix] = fmaxf(acc[im][ix], 0.f);
#pragma unroll
    for (int j = 0; j < 3; ++j) {
#pragma unroll
        for (int q = 0; q < 2; ++q) {
            float4 v;
            float s0 = 0.f, s1 = 0.f, s2 = 0.f, s3 = 0.f;
#pragma unroll
            for (int im = 0; im < 8; ++im) {
                s0 = fmaf(w2v[j][im], acc[im][q * 4 + 0], s0);
                s1 = fmaf(w2v[j][im], acc[im][q * 4 + 1], s1);
                s2 = fmaf(w2v[j][im], acc[im][q * 4 + 2], s2);
                s3 = fmaf(w2v[j][im], acc[im][q * 4 + 3], s3);
            }
            v.x = s0; v.y = s1; v.z = s2; v.w = s3;
            sW4[tm * 48 + j * 16 + tx * 2 + q] = v;
        }
    }
    __syncthreads();
#pragma unroll
    for (int r = 0; r < 2; ++r) {
        int idx = t + r * 128;
        if (idx < 192) {
            int j = idx >> 6, x = idx & 63;
            float s = b2[j];
#pragma unroll
            for (int g = 0; g < 16; ++g) s += sW[g * 192 + j * 64 + x];
            out[(size_t)(b * 3 + j) * HW + y * 256 + x0 + x] = s;
        }
    }
}

extern "C" void kernel_launch(void* const* d_in, const int* in_sizes, int n_in,
                              void* d_out, int out_size, void* d_ws, size_t ws_size,
                              hipStream_t stream) {
    const float* x     = (const float*)d_in[0];
    const float* fc0_w = (const float*)d_in[1];
    const float* fc0_b = (const float*)d_in[2];
    const float* swre  = (const float*)d_in[3];
    const float* swim  = (const float*)d_in[4];
    const float* ww    = (const float*)d_in[5];
    const float* wb    = (const float*)d_in[6];
    const float* fc1w  = (const float*)d_in[7];
    const float* fc1b  = (const float*)d_in[8];
    const float* fc2w  = (const float*)d_in[9];
    const float* fc2b  = (const float*)d_in[10];

    float* ws = (float*)d_ws;
    float2* tab    = (float2*)ws;                     // 512 floats
    float*  h      = ws + 512;                        // 33,554,432
    float*  T1F    = ws + 33554944;                   // 4,194,304 (planar 512x32x256)
    float2* X      = (float2*)(ws + 37749248);        // 262,144 floats
    float2* Y      = (float2*)(ws + 38011392);        // 262,144 floats
    float*  Gq     = ws + 38273536;                   // 4,194,304
    float*  wwT    = ws + 42467840;                   // 16,384 (4 layers)
    float*  w1T    = ws + 42484224;                   // 8,192
    float*  trig   = ws + 42492416;                   // 8,192
    float*  trigFT = ws + 42500608;                   // 8,192

    k_table<<<dim3(1), dim3(256), 0, stream>>>(tab);
    k_prep0<<<dim3(160), dim3(256), 0, stream>>>(tab, fc1w, ww, trig, trigFT, w1T, wwT);
    k_fc0<<<dim3(2048), dim3(256), 0, stream>>>(x, fc0_w, fc0_b, h);

    for (int d = 0; d < NDEPTH; ++d) {
        k_fwd_y<<<dim3(512), dim3(128), 0, stream>>>(h, trigFT, T1F);
        k_fwd_x<<<dim3(512), dim3(256), 0, stream>>>(T1F, tab, X);
        k_mix<<<dim3(256), dim3(256), 0, stream>>>(X, swre + (size_t)d * C * C * 256,
                                                   swim + (size_t)d * C * C * 256, Y);
        k_invy<<<dim3(512), dim3(256), 0, stream>>>(Y, tab, Gq);
        k_final<<<dim3(2048), dim3(256), 0, stream>>>(h, Gq, wwT + d * 4096, wb + d * C, trig);
    }
    k_fc12<<<dim3(8192), dim3(128), 0, stream>>>(h, w1T, fc1b, fc2w, fc2b, (float*)d_out);
}

// Round 12
// 933.951 us; speedup vs baseline: 6.4239x; 1.0061x over previous
//
#include <hip/hip_runtime.h>

#define Hd 256
#define Wd 256
#define HW 65536
#define C 64
#define B 8
#define M 16
#define NDEPTH 4
#define NMLP 128

// ---------------- twiddle table: e^{2*pi*i*t/256}, double-precision accurate --------------
__global__ void k_table(float2* __restrict__ tab) {
    int t = threadIdx.x;
    double a = (6.283185307179586476925286766559 / 256.0) * (double)t;
    tab[t] = make_float2((float)cos(a), (float)sin(a));
}

// ---------------- once: trig (final/fwd_x), trigFT (fwd_y), w1T, wwT_all ----------------
__global__ void k_prep0(const float2* __restrict__ tab, const float* __restrict__ fc1w,
                        const float* __restrict__ ww,
                        float* __restrict__ trig, float* __restrict__ trigFT,
                        float* __restrict__ w1T, float* __restrict__ wwT_all) {
    int blk = blockIdx.x, t = threadIdx.x;
    if (blk < 32) {                    // trig[kk][x]: cos for kk<16, +sin for kk>=16
        int k = blk & 15;
        float2 e = tab[(k * t) & 255];
        trig[blk * 256 + t] = (blk < 16) ? e.x : e.y;
    } else if (blk < 64) {             // trigFT[y][kk]: cos for kk<16, -sin for kk>=16
        int f = (blk - 32) * 256 + t;  // 0..8191
        int y = f >> 5, kk = f & 31;
        float2 e = tab[((kk & 15) * y) & 255];
        trigFT[f] = (kk < 16) ? e.x : -e.y;
    } else if (blk < 96) {             // w1T[i][m] = fc1w[m][i]
        int f = (blk - 64) * 256 + t;  // 0..8191
        int i = f >> 7, m = f & 127;
        w1T[f] = fc1w[m * 64 + i];
    } else {                           // wwT_all[d][i][o] = ww[d][o][i]
        int f = (blk - 96) * 256 + t;  // 0..16383
        int d = f >> 12, r = f & 4095;
        int i = r >> 6, o = r & 63;
        wwT_all[f] = ww[d * 4096 + o * 64 + i];
    }
}

// ---------------- fc0: 3 -> 64 channels, per pixel ----------------
__global__ void k_fc0(const float* __restrict__ x, const float* __restrict__ w,
                      const float* __restrict__ bias, float* __restrict__ h) {
    int p = blockIdx.x * 256 + threadIdx.x;
    int b = p >> 16, pix = p & 65535;
    float x0 = x[(b * 3 + 0) * HW + pix];
    float x1 = x[(b * 3 + 1) * HW + pix];
    float x2 = x[(b * 3 + 2) * HW + pix];
    for (int o = 0; o < C; ++o) {
        float v = bias[o];
        v = fmaf(w[o * 3 + 0], x0, v);
        v = fmaf(w[o * 3 + 1], x1, v);
        v = fmaf(w[o * 3 + 2], x2, v);
        h[(b * C + o) * HW + pix] = v;
    }
}

// ---------------- forward y-DFT as GEMM: T1F[bc][r][w] = sum_y trigF[r][y] h[bc][y][w] ----
// R12: conflict-free x-split — thread owns w = cg*4..+3 and 128+cg*4..+3 so each b128
// read is 32 dense consecutive float4s per wave (old cg*2 pattern was 8-way conflicted:
// 8*cg%32 hits only {0,8,16,24}).
__global__ __launch_bounds__(128, 2)
void k_fwd_y(const float* __restrict__ h, const float* __restrict__ trigFT,
             float* __restrict__ T1F) {
    __shared__ float sH[32 * 256];   // 32 KB
    __shared__ float sE[32 * 32];    // 4 KB, [y][kk]
    int bc = blockIdx.x, t = threadIdx.x;
    int rg = t >> 5, cg = t & 31;    // 4 row-groups (8 rows), 32 col-groups
    float acc[8][8];
#pragma unroll
    for (int io = 0; io < 8; ++io)
#pragma unroll
        for (int ix = 0; ix < 8; ++ix) acc[io][ix] = 0.f;
    float4* sH4 = (float4*)sH;
    float4* sE4 = (float4*)sE;
    for (int ph = 0; ph < 8; ++ph) {
#pragma unroll
        for (int p = 0; p < 16; ++p) {     // 2048 float4, coalesced
            int f = t + p * 128;
            sH4[f] = *(const float4*)(h + (size_t)bc * HW + ph * 32 * 256 + f * 4);
        }
#pragma unroll
        for (int p = 0; p < 2; ++p) {      // 256 float4
            int f = t + p * 128;
            sE4[f] = *(const float4*)(trigFT + ph * 1024 + f * 4);
        }
        __syncthreads();
#pragma unroll 4
        for (int yy = 0; yy < 32; ++yy) {
            float4 e0 = sE4[yy * 8 + rg * 2], e1 = sE4[yy * 8 + rg * 2 + 1];
            float4 h0 = sH4[yy * 64 + cg];        // w = cg*4..+3   (dense per wave)
            float4 h1 = sH4[yy * 64 + 32 + cg];   // w = 128+cg*4..+3
            float ae[8] = {e0.x, e0.y, e0.z, e0.w, e1.x, e1.y, e1.z, e1.w};
            float ah[8] = {h0.x, h0.y, h0.z, h0.w, h1.x, h1.y, h1.z, h1.w};
#pragma unroll
            for (int io = 0; io < 8; ++io)
#pragma unroll
                for (int ix = 0; ix < 8; ++ix)
                    acc[io][ix] = fmaf(ae[io], ah[ix], acc[io][ix]);
        }
        __syncthreads();
    }
#pragma unroll
    for (int io = 0; io < 8; ++io) {
        float* dst = T1F + (size_t)bc * 8192 + (rg * 8 + io) * 256;
        float4 v0, v1;
        v0.x = acc[io][0]; v0.y = acc[io][1]; v0.z = acc[io][2]; v0.w = acc[io][3];
        v1.x = acc[io][4]; v1.y = acc[io][5]; v1.z = acc[io][6]; v1.w = acc[io][7];
        *(float4*)(dst + cg * 4) = v0;
        *(float4*)(dst + 128 + cg * 4) = v1;
    }
}

// ---------------- forward x-DFT: X[bc, ky*16+kx] from planar T1F ----------------
// R12: float4 over w with the precomputed cos/sin planes (trig) staged in LDS —
// kills the per-lane (kx*w)&255 index math and 768 scalar LDS reads of the old
// version. Rows padded to 260 floats (65 float4) so distinct ky/kx rows spread banks.
__global__ __launch_bounds__(256, 2)
void k_fwd_x(const float* __restrict__ T1F, const float* __restrict__ trig,
             float2* __restrict__ X) {
    __shared__ float sT[32 * 260];    // 33.3 KB  T1F rows (padded)
    __shared__ float sG[32 * 260];    // 33.3 KB  cos/sin rows (padded)
    int bc = blockIdx.x, t = threadIdx.x;
#pragma unroll
    for (int p = 0; p < 8; ++p) {     // 2048 float4 each
        int f = t + p * 256;
        int row = f >> 6, seg = f & 63;
        ((float4*)(sT + row * 260))[seg] = *(const float4*)(T1F + (size_t)bc * 8192 + f * 4);
        ((float4*)(sG + row * 260))[seg] = *(const float4*)(trig + row * 256 + seg * 4);
    }
    __syncthreads();
    int ky = t >> 4, kx = t & 15;
    const float* Tr = sT + ky * 260;
    const float* Ti = sT + (16 + ky) * 260;
    const float* Cs = sG + kx * 260;
    const float* Sn = sG + (16 + kx) * 260;
    float xr0 = 0.f, xi0 = 0.f, xr1 = 0.f, xi1 = 0.f;
    for (int q = 0; q < 64; q += 2) {
        float4 tr = *(const float4*)(Tr + q * 4);
        float4 ti = *(const float4*)(Ti + q * 4);
        float4 cs = *(const float4*)(Cs + q * 4);
        float4 sn = *(const float4*)(Sn + q * 4);
        xr0 = fmaf(tr.x, cs.x, xr0); xr0 = fmaf(ti.x, sn.x, xr0);
        xi0 = fmaf(ti.x, cs.x, xi0); xi0 = fmaf(-tr.x, sn.x, xi0);
        xr0 = fmaf(tr.y, cs.y, xr0); xr0 = fmaf(ti.y, sn.y, xr0);
        xi0 = fmaf(ti.y, cs.y, xi0); xi0 = fmaf(-tr.y, sn.y, xi0);
        xr0 = fmaf(tr.z, cs.z, xr0); xr0 = fmaf(ti.z, sn.z, xr0);
        xi0 = fmaf(ti.z, cs.z, xi0); xi0 = fmaf(-tr.z, sn.z, xi0);
        xr0 = fmaf(tr.w, cs.w, xr0); xr0 = fmaf(ti.w, sn.w, xr0);
        xi0 = fmaf(ti.w, cs.w, xi0); xi0 = fmaf(-tr.w, sn.w, xi0);
        float4 tr1 = *(const float4*)(Tr + q * 4 + 4);
        float4 ti1 = *(const float4*)(Ti + q * 4 + 4);
        float4 cs1 = *(const float4*)(Cs + q * 4 + 4);
        float4 sn1 = *(const float4*)(Sn + q * 4 + 4);
        xr1 = fmaf(tr1.x, cs1.x, xr1); xr1 = fmaf(ti1.x, sn1.x, xr1);
        xi1 = fmaf(ti1.x, cs1.x, xi1); xi1 = fmaf(-tr1.x, sn1.x, xi1);
        xr1 = fmaf(tr1.y, cs1.y, xr1); xr1 = fmaf(ti1.y, sn1.y, xr1);
        xi1 = fmaf(ti1.y, cs1.y, xi1); xi1 = fmaf(-tr1.y, sn1.y, xi1);
        xr1 = fmaf(tr1.z, cs1.z, xr1); xr1 = fmaf(ti1.z, sn1.z, xr1);
        xi1 = fmaf(ti1.z, cs1.z, xi1); xi1 = fmaf(-tr1.z, sn1.z, xi1);
        xr1 = fmaf(tr1.w, cs1.w, xr1); xr1 = fmaf(ti1.w, sn1.w, xr1);
        xi1 = fmaf(ti1.w, cs1.w, xi1); xi1 = fmaf(-tr1.w, sn1.w, xi1);
    }
    X[bc * 256 + t] = make_float2(xr0 + xr1, xi0 + xi1);
}

// ---------------- mode mixing ----------------
__global__ __launch_bounds__(256, 2)
void k_mix(const float2* __restrict__ X, const float* __restrict__ wre,
           const float* __restrict__ wim, float2* __restrict__ Y) {
    int o = blockIdx.x >> 2;
    int bq = blockIdx.x & 3;
    int m = threadIdx.x;
    int b0 = bq * 2, b1 = bq * 2 + 1;
    float yr0 = 0.f, yi0 = 0.f, yr1 = 0.f, yi1 = 0.f;
    for (int i = 0; i < C; ++i) {
        float wr = wre[(i * C + o) * 256 + m];
        float wi = wim[(i * C + o) * 256 + m];
        float2 x0 = X[(b0 * C + i) * 256 + m];
        float2 x1 = X[(b1 * C + i) * 256 + m];
        yr0 = fmaf(x0.x, wr, fmaf(-x0.y, wi, yr0));
        yi0 = fmaf(x0.x, wi, fmaf(x0.y, wr, yi0));
        yr1 = fmaf(x1.x, wr, fmaf(-x1.y, wi, yr1));
        yi1 = fmaf(x1.x, wi, fmaf(x1.y, wr, yi1));
    }
    Y[(b0 * C + o) * 256 + m] = make_float2(yr0, yi0);
    Y[(b1 * C + o) * 256 + m] = make_float2(yr1, yi1);
}

// ---------------- fused inverse-y + Gq production ----------------
__global__ __launch_bounds__(256, 2)
void k_invy(const float2* __restrict__ Y, const float2* __restrict__ tab,
            float* __restrict__ Gq) {
    __shared__ float2 st[256];
    int blk = blockIdx.x;              // 8b x 4pg x 16yt
    int yt = blk & 15, pg = (blk >> 4) & 3, b = blk >> 6;
    int t = threadIdx.x;
    st[t] = tab[t];
    int o = t & 63, kx = pg * 4 + (t >> 6);
    __syncthreads();
    float sc = (kx == 0 ? 1.0f : 2.0f) * (1.0f / 65536.0f);
    float yr[16], yi[16];
    const float2* yp = Y + (size_t)(b * 64 + o) * 256 + kx;
#pragma unroll
    for (int ky = 0; ky < 16; ++ky) {
        float2 v = yp[ky * 16];
        yr[ky] = v.x * sc;
        yi[ky] = v.y * sc;
    }
    int y0 = yt * 16;
    for (int yy = 0; yy < 16; ++yy) {
        int y = y0 + yy;
        float re = 0.f, im = 0.f;
#pragma unroll
        for (int ky = 0; ky < 16; ++ky) {
            float2 e = st[(ky * y) & 255];   // wave-uniform broadcast
            re = fmaf(yr[ky], e.x, re);
            re = fmaf(-yi[ky], e.y, re);
            im = fmaf(yr[ky], e.y, im);
            im = fmaf(yi[ky], e.x, im);
        }
        float* gp = Gq + (size_t)(b * 256 + y) * 32 * 64 + o;
        gp[kx * 64] = re;
        gp[(16 + kx) * 64] = -im;
    }
}

// ---------------- k_final as augmented GEMM ----------------
// R12: conflict-free x-split (thread owns x = tx*4..+3 and 128+tx*4..+3): each b128
// read/store is 32 dense consecutive float4s per wave. Old tx*2 pattern was 8-way
// conflicted (2.9x LDS cost -> LDS pipe was binding).
__global__ __launch_bounds__(256, 2)
void k_final(float* __restrict__ h, const float* __restrict__ Gq,
             const float* __restrict__ wwT, const float* __restrict__ wb,
             const float* __restrict__ trig) {
    __shared__ float sH[32 * 256];     // 32 KB
    __shared__ float sW[32 * 64];      // 8 KB
    int blk = blockIdx.x;              // b(8) * y(256)
    int y = blk & 255, b = blk >> 8;
    int t = threadIdx.x;
    int to = t >> 5, tx = t & 31;
    float acc[8][8];
#pragma unroll
    for (int io = 0; io < 8; ++io) {
        float bv = wb[to * 8 + io];
#pragma unroll
        for (int ix = 0; ix < 8; ++ix) acc[io][ix] = bv;
    }
    float4* sH4 = (float4*)sH;
    float4* sW4 = (float4*)sW;
    for (int ph = 0; ph < 3; ++ph) {
        int kbase = ph * 32;
        if (ph < 2) {
#pragma unroll
            for (int p = 0; p < 8; ++p) {
                int f = t + p * 256;
                int row = f >> 6, seg = f & 63;
                sH4[f] = *(const float4*)(h + (size_t)(b * 64 + kbase + row) * HW + y * 256 + seg * 4);
            }
#pragma unroll
            for (int p = 0; p < 2; ++p) {
                int f = t + p * 256;
                int row = f >> 4, seg = f & 15;
                sW4[f] = *(const float4*)(wwT + (kbase + row) * 64 + seg * 4);
            }
        } else {
#pragma unroll
            for (int p = 0; p < 8; ++p) {
                int f = t + p * 256;
                int row = f >> 6, seg = f & 63;
                sH4[f] = *(const float4*)(trig + row * 256 + seg * 4);
            }
#pragma unroll
            for (int p = 0; p < 2; ++p) {
                int f = t + p * 256;
                int row = f >> 4, seg = f & 15;
                sW4[f] = *(const float4*)(Gq + ((size_t)(b * 256 + y) * 32 + row) * 64 + seg * 4);
            }
        }
        __syncthreads();
#pragma unroll 4
        for (int kk = 0; kk < 32; ++kk) {
            float4 w0 = sW4[kk * 16 + to * 2], w1 = sW4[kk * 16 + to * 2 + 1];
            float4 h0 = sH4[kk * 64 + tx];        // x = tx*4..+3     (dense)
            float4 h1 = sH4[kk * 64 + 32 + tx];   // x = 128+tx*4..+3 (dense)
            float aw[8] = {w0.x, w0.y, w0.z, w0.w, w1.x, w1.y, w1.z, w1.w};
            float ah[8] = {h0.x, h0.y, h0.z, h0.w, h1.x, h1.y, h1.z, h1.w};
#pragma unroll
            for (int io = 0; io < 8; ++io)
#pragma unroll
                for (int ix = 0; ix < 8; ++ix)
                    acc[io][ix] = fmaf(aw[io], ah[ix], acc[io][ix]);
        }
        __syncthreads();
    }
#pragma unroll
    for (int io = 0; io < 8; ++io) {
        float* dst = h + (size_t)(b * 64 + to * 8 + io) * HW + y * 256;
        float4 v0, v1;
        v0.x = fmaxf(acc[io][0], 0.f); v0.y = fmaxf(acc[io][1], 0.f);
        v0.z = fmaxf(acc[io][2], 0.f); v0.w = fmaxf(acc[io][3], 0.f);
        v1.x = fmaxf(acc[io][4], 0.f); v1.y = fmaxf(acc[io][5], 0.f);
        v1.z = fmaxf(acc[io][6], 0.f); v1.w = fmaxf(acc[io][7], 0.f);
        *(float4*)(dst + tx * 4) = v0;
        *(float4*)(dst + 128 + tx * 4) = v1;
    }
}

// ---------------- fc1+fc2 as GEMM (unchanged; its conflicts cost ~96 cyc/block) --------
__global__ __launch_bounds__(128, 2)
void k_fc12(const float* __restrict__ h, const float* __restrict__ w1T,
            const float* __restrict__ b1, const float* __restrict__ w2,
            const float* __restrict__ b2, float* __restrict__ out) {
    __shared__ float sH[32 * 64];       // 8 KB
    __shared__ float sW[32 * 128];      // 16 KB; reused as part[16][3][64]
    int blk = blockIdx.x;               // b(8)*y(256)*xq(4)
    int xq = blk & 3, y = (blk >> 2) & 255, b = blk >> 10;
    int x0 = xq * 64;
    int t = threadIdx.x;
    int tm = t >> 3, tx = t & 7;
    float acc[8][8];
#pragma unroll
    for (int im = 0; im < 8; ++im) {
        float bv = b1[tm * 8 + im];
#pragma unroll
        for (int ix = 0; ix < 8; ++ix) acc[im][ix] = bv;
    }
    float4* sH4 = (float4*)sH;
    float4* sW4 = (float4*)sW;
    for (int ph = 0; ph < 2; ++ph) {
#pragma unroll
        for (int p = 0; p < 4; ++p) {
            int f = t + p * 128;
            int row = f >> 4, seg = f & 15;
            sH4[f] = *(const float4*)(h + (size_t)(b * 64 + ph * 32 + row) * HW + y * 256 + x0 + seg * 4);
        }
#pragma unroll
        for (int p = 0; p < 8; ++p) {
            int f = t + p * 128;
            int row = f >> 5, seg = f & 31;
            sW4[f] = *(const float4*)(w1T + (ph * 32 + row) * 128 + seg * 4);
        }
        __syncthreads();
#pragma unroll 4
        for (int kk = 0; kk < 32; ++kk) {
            float4 w0 = sW4[kk * 32 + tm * 2], w1 = sW4[kk * 32 + tm * 2 + 1];
            float4 h0 = sH4[kk * 16 + tx * 2], h1 = sH4[kk * 16 + tx * 2 + 1];
            float aw[8] = {w0.x, w0.y, w0.z, w0.w, w1.x, w1.y, w1.z, w1.w};
            float ah[8] = {h0.x, h0.y, h0.z, h0.w, h1.x, h1.y, h1.z, h1.w};
#pragma unroll
            for (int im = 0; im < 8; ++im)
#pragma unroll
                for (int ix = 0; ix < 8; ++ix)
                    acc[im][ix] = fmaf(aw[im], ah[ix], acc[im][ix]);
        }
        __syncthreads();
    }
    float w2v[3][8];
#pragma unroll
    for (int j = 0; j < 3; ++j)
#pragma unroll
        for (int im = 0; im < 8; ++im) w2v[j][im] = w2[j * NMLP + tm * 8 + im];
#pragma unroll
    for (int im = 0; im < 8; ++im)
#pragma unroll
        for (int ix = 0; ix < 8; ++ix) acc[im][ix] = fmaxf(acc[im][ix], 0.f);
#pragma unroll
    for (int j = 0; j < 3; ++j) {
#pragma unroll
        for (int q = 0; q < 2; ++q) {
            float4 v;
            float s0 = 0.f, s1 = 0.f, s2 = 0.f, s3 = 0.f;
#pragma unroll
            for (int im = 0; im < 8; ++im) {
                s0 = fmaf(w2v[j][im], acc[im][q * 4 + 0], s0);
                s1 = fmaf(w2v[j][im], acc[im][q * 4 + 1], s1);
                s2 = fmaf(w2v[j][im], acc[im][q * 4 + 2], s2);
                s3 = fmaf(w2v[j][im], acc[im][q * 4 + 3], s3);
            }
            v.x = s0; v.y = s1; v.z = s2; v.w = s3;
            sW4[tm * 48 + j * 16 + tx * 2 + q] = v;
        }
    }
    __syncthreads();
#pragma unroll
    for (int r = 0; r < 2; ++r) {
        int idx = t + r * 128;
        if (idx < 192) {
            int j = idx >> 6, x = idx & 63;
            float s = b2[j];
#pragma unroll
            for (int g = 0; g < 16; ++g) s += sW[g * 192 + j * 64 + x];
            out[(size_t)(b * 3 + j) * HW + y * 256 + x0 + x] = s;
        }
    }
}

extern "C" void kernel_launch(void* const* d_in, const int* in_sizes, int n_in,
                              void* d_out, int out_size, void* d_ws, size_t ws_size,
                              hipStream_t stream) {
    const float* x     = (const float*)d_in[0];
    const float* fc0_w = (const float*)d_in[1];
    const float* fc0_b = (const float*)d_in[2];
    const float* swre  = (const float*)d_in[3];
    const float* swim  = (const float*)d_in[4];
    const float* ww    = (const float*)d_in[5];
    const float* wb    = (const float*)d_in[6];
    const float* fc1w  = (const float*)d_in[7];
    const float* fc1b  = (const float*)d_in[8];
    const float* fc2w  = (const float*)d_in[9];
    const float* fc2b  = (const float*)d_in[10];

    float* ws = (float*)d_ws;
    float2* tab    = (float2*)ws;                     // 512 floats
    float*  h      = ws + 512;                        // 33,554,432
    float*  T1F    = ws + 33554944;                   // 4,194,304 (planar 512x32x256)
    float2* X      = (float2*)(ws + 37749248);        // 262,144 floats
    float2* Y      = (float2*)(ws + 38011392);        // 262,144 floats
    float*  Gq     = ws + 38273536;                   // 4,194,304
    float*  wwT    = ws + 42467840;                   // 16,384 (4 layers)
    float*  w1T    = ws + 42484224;                   // 8,192
    float*  trig   = ws + 42492416;                   // 8,192
    float*  trigFT = ws + 42500608;                   // 8,192

    k_table<<<dim3(1), dim3(256), 0, stream>>>(tab);
    k_prep0<<<dim3(160), dim3(256), 0, stream>>>(tab, fc1w, ww, trig, trigFT, w1T, wwT);
    k_fc0<<<dim3(2048), dim3(256), 0, stream>>>(x, fc0_w, fc0_b, h);

    for (int d = 0; d < NDEPTH; ++d) {
        k_fwd_y<<<dim3(512), dim3(128), 0, stream>>>(h, trigFT, T1F);
        k_fwd_x<<<dim3(512), dim3(256), 0, stream>>>(T1F, trig, X);
        k_mix<<<dim3(256), dim3(256), 0, stream>>>(X, swre + (size_t)d * C * C * 256,
                                                   swim + (size_t)d * C * C * 256, Y);
        k_invy<<<dim3(512), dim3(256), 0, stream>>>(Y, tab, Gq);
        k_final<<<dim3(2048), dim3(256), 0, stream>>>(h, Gq, wwT + d * 4096, wb + d * C, trig);
    }
    k_fc12<<<dim3(8192), dim3(128), 0, stream>>>(h, w1T, fc1b, fc2w, fc2b, (float*)d_out);
}

// Round 13
// 902.423 us; speedup vs baseline: 6.6483x; 1.0349x over previous
//
#include <hip/hip_runtime.h>

#define Hd 256
#define Wd 256
#define HW 65536
#define C 64
#define B 8
#define M 16
#define NDEPTH 4
#define NMLP 128

// ---------------- twiddle table ----------------
__global__ void k_table(float2* __restrict__ tab) {
    int t = threadIdx.x;
    double a = (6.283185307179586476925286766559 / 256.0) * (double)t;
    tab[t] = make_float2((float)cos(a), (float)sin(a));
}

// ---------------- once: trig, trigFT, w1T, wwT_all ----------------
__global__ void k_prep0(const float2* __restrict__ tab, const float* __restrict__ fc1w,
                        const float* __restrict__ ww,
                        float* __restrict__ trig, float* __restrict__ trigFT,
                        float* __restrict__ w1T, float* __restrict__ wwT_all) {
    int blk = blockIdx.x, t = threadIdx.x;
    if (blk < 32) {                    // trig[kk][x]: cos kk<16, +sin kk>=16
        int k = blk & 15;
        float2 e = tab[(k * t) & 255];
        trig[blk * 256 + t] = (blk < 16) ? e.x : e.y;
    } else if (blk < 64) {             // trigFT[y][kk]: cos kk<16, -sin kk>=16
        int f = (blk - 32) * 256 + t;
        int y = f >> 5, kk = f & 31;
        float2 e = tab[((kk & 15) * y) & 255];
        trigFT[f] = (kk < 16) ? e.x : -e.y;
    } else if (blk < 96) {             // w1T[i][m] = fc1w[m][i]
        int f = (blk - 64) * 256 + t;
        int i = f >> 7, m = f & 127;
        w1T[f] = fc1w[m * 64 + i];
    } else {                           // wwT_all[d][i][o] = ww[d][o][i]
        int f = (blk - 96) * 256 + t;
        int d = f >> 12, r = f & 4095;
        int i = r >> 6, o = r & 63;
        wwT_all[f] = ww[d * 4096 + o * 64 + i];
    }
}

// ---------------- fc0 ----------------
__global__ void k_fc0(const float* __restrict__ x, const float* __restrict__ w,
                      const float* __restrict__ bias, float* __restrict__ h) {
    int p = blockIdx.x * 256 + threadIdx.x;
    int b = p >> 16, pix = p & 65535;
    float x0 = x[(b * 3 + 0) * HW + pix];
    float x1 = x[(b * 3 + 1) * HW + pix];
    float x2 = x[(b * 3 + 2) * HW + pix];
    for (int o = 0; o < C; ++o) {
        float v = bias[o];
        v = fmaf(w[o * 3 + 0], x0, v);
        v = fmaf(w[o * 3 + 1], x1, v);
        v = fmaf(w[o * 3 + 2], x2, v);
        h[(b * C + o) * HW + pix] = v;
    }
}

// ---------------- forward y-DFT as GEMM (unchanged from R12) ----------------
__global__ __launch_bounds__(128, 2)
void k_fwd_y(const float* __restrict__ h, const float* __restrict__ trigFT,
             float* __restrict__ T1F) {
    __shared__ float sH[32 * 256];   // 32 KB
    __shared__ float sE[32 * 32];    // 4 KB
    int bc = blockIdx.x, t = threadIdx.x;
    int rg = t >> 5, cg = t & 31;
    float acc[8][8];
#pragma unroll
    for (int io = 0; io < 8; ++io)
#pragma unroll
        for (int ix = 0; ix < 8; ++ix) acc[io][ix] = 0.f;
    float4* sH4 = (float4*)sH;
    float4* sE4 = (float4*)sE;
    for (int ph = 0; ph < 8; ++ph) {
#pragma unroll
        for (int p = 0; p < 16; ++p) {
            int f = t + p * 128;
            sH4[f] = *(const float4*)(h + (size_t)bc * HW + ph * 32 * 256 + f * 4);
        }
#pragma unroll
        for (int p = 0; p < 2; ++p) {
            int f = t + p * 128;
            sE4[f] = *(const float4*)(trigFT + ph * 1024 + f * 4);
        }
        __syncthreads();
#pragma unroll 4
        for (int yy = 0; yy < 32; ++yy) {
            float4 e0 = sE4[yy * 8 + rg * 2], e1 = sE4[yy * 8 + rg * 2 + 1];
            float4 h0 = sH4[yy * 64 + cg];
            float4 h1 = sH4[yy * 64 + 32 + cg];
            float ae[8] = {e0.x, e0.y, e0.z, e0.w, e1.x, e1.y, e1.z, e1.w};
            float ah[8] = {h0.x, h0.y, h0.z, h0.w, h1.x, h1.y, h1.z, h1.w};
#pragma unroll
            for (int io = 0; io < 8; ++io)
#pragma unroll
                for (int ix = 0; ix < 8; ++ix)
                    acc[io][ix] = fmaf(ae[io], ah[ix], acc[io][ix]);
        }
        __syncthreads();
    }
#pragma unroll
    for (int io = 0; io < 8; ++io) {
        float* dst = T1F + (size_t)bc * 8192 + (rg * 8 + io) * 256;
        float4 v0, v1;
        v0.x = acc[io][0]; v0.y = acc[io][1]; v0.z = acc[io][2]; v0.w = acc[io][3];
        v1.x = acc[io][4]; v1.y = acc[io][5]; v1.z = acc[io][6]; v1.w = acc[io][7];
        *(float4*)(dst + cg * 4) = v0;
        *(float4*)(dst + 128 + cg * 4) = v1;
    }
}

// ---------------- forward x-DFT (unchanged from R12) ----------------
__global__ __launch_bounds__(256, 2)
void k_fwd_x(const float* __restrict__ T1F, const float* __restrict__ trig,
             float2* __restrict__ X) {
    __shared__ float sT[32 * 260];
    __shared__ float sG[32 * 260];
    int bc = blockIdx.x, t = threadIdx.x;
#pragma unroll
    for (int p = 0; p < 8; ++p) {
        int f = t + p * 256;
        int row = f >> 6, seg = f & 63;
        ((float4*)(sT + row * 260))[seg] = *(const float4*)(T1F + (size_t)bc * 8192 + f * 4);
        ((float4*)(sG + row * 260))[seg] = *(const float4*)(trig + row * 256 + seg * 4);
    }
    __syncthreads();
    int ky = t >> 4, kx = t & 15;
    const float* Tr = sT + ky * 260;
    const float* Ti = sT + (16 + ky) * 260;
    const float* Cs = sG + kx * 260;
    const float* Sn = sG + (16 + kx) * 260;
    float xr0 = 0.f, xi0 = 0.f, xr1 = 0.f, xi1 = 0.f;
    for (int q = 0; q < 64; q += 2) {
        float4 tr = *(const float4*)(Tr + q * 4);
        float4 ti = *(const float4*)(Ti + q * 4);
        float4 cs = *(const float4*)(Cs + q * 4);
        float4 sn = *(const float4*)(Sn + q * 4);
        xr0 = fmaf(tr.x, cs.x, xr0); xr0 = fmaf(ti.x, sn.x, xr0);
        xi0 = fmaf(ti.x, cs.x, xi0); xi0 = fmaf(-tr.x, sn.x, xi0);
        xr0 = fmaf(tr.y, cs.y, xr0); xr0 = fmaf(ti.y, sn.y, xr0);
        xi0 = fmaf(ti.y, cs.y, xi0); xi0 = fmaf(-tr.y, sn.y, xi0);
        xr0 = fmaf(tr.z, cs.z, xr0); xr0 = fmaf(ti.z, sn.z, xr0);
        xi0 = fmaf(ti.z, cs.z, xi0); xi0 = fmaf(-tr.z, sn.z, xi0);
        xr0 = fmaf(tr.w, cs.w, xr0); xr0 = fmaf(ti.w, sn.w, xr0);
        xi0 = fmaf(ti.w, cs.w, xi0); xi0 = fmaf(-tr.w, sn.w, xi0);
        float4 tr1 = *(const float4*)(Tr + q * 4 + 4);
        float4 ti1 = *(const float4*)(Ti + q * 4 + 4);
        float4 cs1 = *(const float4*)(Cs + q * 4 + 4);
        float4 sn1 = *(const float4*)(Sn + q * 4 + 4);
        xr1 = fmaf(tr1.x, cs1.x, xr1); xr1 = fmaf(ti1.x, sn1.x, xr1);
        xi1 = fmaf(ti1.x, cs1.x, xi1); xi1 = fmaf(-tr1.x, sn1.x, xi1);
        xr1 = fmaf(tr1.y, cs1.y, xr1); xr1 = fmaf(ti1.y, sn1.y, xr1);
        xi1 = fmaf(ti1.y, cs1.y, xi1); xi1 = fmaf(-tr1.y, sn1.y, xi1);
        xr1 = fmaf(tr1.z, cs1.z, xr1); xr1 = fmaf(ti1.z, sn1.z, xr1);
        xi1 = fmaf(ti1.z, cs1.z, xi1); xi1 = fmaf(-tr1.z, sn1.z, xi1);
        xr1 = fmaf(tr1.w, cs1.w, xr1); xr1 = fmaf(ti1.w, sn1.w, xr1);
        xi1 = fmaf(ti1.w, cs1.w, xi1); xi1 = fmaf(-tr1.w, sn1.w, xi1);
    }
    X[bc * 256 + t] = make_float2(xr0 + xr1, xi0 + xi1);
}

// ---------------- mode mixing (unchanged) ----------------
__global__ __launch_bounds__(256, 2)
void k_mix(const float2* __restrict__ X, const float* __restrict__ wre,
           const float* __restrict__ wim, float2* __restrict__ Y) {
    int o = blockIdx.x >> 2;
    int bq = blockIdx.x & 3;
    int m = threadIdx.x;
    int b0 = bq * 2, b1 = bq * 2 + 1;
    float yr0 = 0.f, yi0 = 0.f, yr1 = 0.f, yi1 = 0.f;
    for (int i = 0; i < C; ++i) {
        float wr = wre[(i * C + o) * 256 + m];
        float wi = wim[(i * C + o) * 256 + m];
        float2 x0 = X[(b0 * C + i) * 256 + m];
        float2 x1 = X[(b1 * C + i) * 256 + m];
        yr0 = fmaf(x0.x, wr, fmaf(-x0.y, wi, yr0));
        yi0 = fmaf(x0.x, wi, fmaf(x0.y, wr, yi0));
        yr1 = fmaf(x1.x, wr, fmaf(-x1.y, wi, yr1));
        yi1 = fmaf(x1.x, wi, fmaf(x1.y, wr, yi1));
    }
    Y[(b0 * C + o) * 256 + m] = make_float2(yr0, yi0);
    Y[(b1 * C + o) * 256 + m] = make_float2(yr1, yi1);
}

// ---------------- fused inverse-y + Gq production (unchanged) ----------------
__global__ __launch_bounds__(256, 2)
void k_invy(const float2* __restrict__ Y, const float2* __restrict__ tab,
            float* __restrict__ Gq) {
    __shared__ float2 st[256];
    int blk = blockIdx.x;              // 8b x 4pg x 16yt
    int yt = blk & 15, pg = (blk >> 4) & 3, b = blk >> 6;
    int t = threadIdx.x;
    st[t] = tab[t];
    int o = t & 63, kx = pg * 4 + (t >> 6);
    __syncthreads();
    float sc = (kx == 0 ? 1.0f : 2.0f) * (1.0f / 65536.0f);
    float yr[16], yi[16];
    const float2* yp = Y + (size_t)(b * 64 + o) * 256 + kx;
#pragma unroll
    for (int ky = 0; ky < 16; ++ky) {
        float2 v = yp[ky * 16];
        yr[ky] = v.x * sc;
        yi[ky] = v.y * sc;
    }
    int y0 = yt * 16;
    for (int yy = 0; yy < 16; ++yy) {
        int y = y0 + yy;
        float re = 0.f, im = 0.f;
#pragma unroll
        for (int ky = 0; ky < 16; ++ky) {
            float2 e = st[(ky * y) & 255];
            re = fmaf(yr[ky], e.x, re);
            re = fmaf(-yi[ky], e.y, re);
            im = fmaf(yr[ky], e.y, im);
            im = fmaf(yi[ky], e.x, im);
        }
        float* gp = Gq + (size_t)(b * 256 + y) * 32 * 64 + o;
        gp[kx * 64] = re;
        gp[(16 + kx) * 64] = -im;
    }
}

// ---------------- k_final as augmented GEMM ----------------
// R13: 64o x 128x tile, 24 KB LDS -> 6 blocks/CU (was 40 KB -> 2). R10/12 counters
// (VALUBusy 46%, Occ 23%) showed the barrier drain after staging was exposed with
// only 1 other resident block; 6-way block residency covers it. acc 8x4.
__global__ __launch_bounds__(256, 2)
void k_final(float* __restrict__ h, const float* __restrict__ Gq,
             const float* __restrict__ wwT, const float* __restrict__ wb,
             const float* __restrict__ trig) {
    __shared__ float sH[32 * 128];     // 16 KB
    __shared__ float sW[32 * 64];      // 8 KB
    int blk = blockIdx.x;              // b(8) * y(256) * xq(2), xq fastest
    int xq = blk & 1, y = (blk >> 1) & 255, b = blk >> 9;
    int x0 = xq * 128;
    int t = threadIdx.x;
    int to = t >> 5, tx = t & 31;      // 8 o-groups (8 o), 32 x-groups (4 x)
    float acc[8][4];
#pragma unroll
    for (int io = 0; io < 8; ++io) {
        float bv = wb[to * 8 + io];
#pragma unroll
        for (int ix = 0; ix < 4; ++ix) acc[io][ix] = bv;
    }
    float4* sH4 = (float4*)sH;
    float4* sW4 = (float4*)sW;
    for (int ph = 0; ph < 3; ++ph) {
        int kbase = ph * 32;
        if (ph < 2) {
#pragma unroll
            for (int p = 0; p < 4; ++p) {      // 1024 float4
                int f = t + p * 256;
                int row = f >> 5, seg = f & 31;
                sH4[f] = *(const float4*)(h + (size_t)(b * 64 + kbase + row) * HW + y * 256 + x0 + seg * 4);
            }
#pragma unroll
            for (int p = 0; p < 2; ++p) {      // 512 float4
                int f = t + p * 256;
                int row = f >> 4, seg = f & 15;
                sW4[f] = *(const float4*)(wwT + (kbase + row) * 64 + seg * 4);
            }
        } else {
#pragma unroll
            for (int p = 0; p < 4; ++p) {
                int f = t + p * 256;
                int row = f >> 5, seg = f & 31;
                sH4[f] = *(const float4*)(trig + row * 256 + x0 + seg * 4);
            }
#pragma unroll
            for (int p = 0; p < 2; ++p) {
                int f = t + p * 256;
                int row = f >> 4, seg = f & 15;
                sW4[f] = *(const float4*)(Gq + ((size_t)(b * 256 + y) * 32 + row) * 64 + seg * 4);
            }
        }
        __syncthreads();
#pragma unroll 4
        for (int kk = 0; kk < 32; ++kk) {
            float4 w0 = sW4[kk * 16 + to * 2], w1 = sW4[kk * 16 + to * 2 + 1];
            float4 h0 = sH4[kk * 32 + tx];     // x = x0 + tx*4..+3 (dense per wave)
            float aw[8] = {w0.x, w0.y, w0.z, w0.w, w1.x, w1.y, w1.z, w1.w};
            float ah[4] = {h0.x, h0.y, h0.z, h0.w};
#pragma unroll
            for (int io = 0; io < 8; ++io)
#pragma unroll
                for (int ix = 0; ix < 4; ++ix)
                    acc[io][ix] = fmaf(aw[io], ah[ix], acc[io][ix]);
        }
        __syncthreads();
    }
#pragma unroll
    for (int io = 0; io < 8; ++io) {
        float* dst = h + (size_t)(b * 64 + to * 8 + io) * HW + y * 256 + x0;
        float4 v;
        v.x = fmaxf(acc[io][0], 0.f); v.y = fmaxf(acc[io][1], 0.f);
        v.z = fmaxf(acc[io][2], 0.f); v.w = fmaxf(acc[io][3], 0.f);
        *(float4*)(dst + tx * 4) = v;
    }
}

// ---------------- fc1+fc2 as GEMM, 128m x 128x tile ----------------
// R13: x-tile 64->128 halves w1T restaging (268->134 MB) and lifts residency
// (32 KB LDS -> 5 blocks/CU, ~5 waves/SIMD vs 3). acc 8x8; m set = {tm*4..+3,
// 64+tm*4..+3}, x set = {tx*4..+3, 64+tx*4..+3}.
__global__ __launch_bounds__(256, 2)
void k_fc12(const float* __restrict__ h, const float* __restrict__ w1T,
            const float* __restrict__ b1, const float* __restrict__ w2,
            const float* __restrict__ b2, float* __restrict__ out) {
    __shared__ float smem[2 * 32 * 128];    // 32 KB: sH | sW; reused as part[16][3][128]
    float* sH = smem;
    float* sW = smem + 32 * 128;
    int blk = blockIdx.x;                   // b(8) * y(256) * xq(2), xq fastest
    int xq = blk & 1, y = (blk >> 1) & 255, b = blk >> 9;
    int x0 = xq * 128;
    int t = threadIdx.x;
    int tm = t >> 4, tx = t & 15;           // 16 m-groups, 16 x-groups
    float acc[8][8];
#pragma unroll
    for (int im = 0; im < 8; ++im) {
        int m = (im < 4) ? (tm * 4 + im) : (64 + tm * 4 + im - 4);
        float bv = b1[m];
#pragma unroll
        for (int ix = 0; ix < 8; ++ix) acc[im][ix] = bv;
    }
    float4* sH4 = (float4*)sH;
    float4* sW4 = (float4*)sW;
    for (int ph = 0; ph < 2; ++ph) {
#pragma unroll
        for (int p = 0; p < 4; ++p) {       // sH: 1024 float4
            int f = t + p * 256;
            int row = f >> 5, seg = f & 31;
            sH4[f] = *(const float4*)(h + (size_t)(b * 64 + ph * 32 + row) * HW + y * 256 + x0 + seg * 4);
        }
#pragma unroll
        for (int p = 0; p < 4; ++p) {       // sW: 1024 float4
            int f = t + p * 256;
            int row = f >> 5, seg = f & 31;
            sW4[f] = *(const float4*)(w1T + (ph * 32 + row) * 128 + seg * 4);
        }
        __syncthreads();
#pragma unroll 4
        for (int kk = 0; kk < 32; ++kk) {
            float4 w0 = sW4[kk * 32 + tm], w1 = sW4[kk * 32 + 16 + tm];
            float4 h0 = sH4[kk * 32 + tx], h1 = sH4[kk * 32 + 16 + tx];
            float aw[8] = {w0.x, w0.y, w0.z, w0.w, w1.x, w1.y, w1.z, w1.w};
            float ah[8] = {h0.x, h0.y, h0.z, h0.w, h1.x, h1.y, h1.z, h1.w};
#pragma unroll
            for (int im = 0; im < 8; ++im)
#pragma unroll
                for (int ix = 0; ix < 8; ++ix)
                    acc[im][ix] = fmaf(aw[im], ah[ix], acc[im][ix]);
        }
        __syncthreads();
    }
    // relu + fc2 partials into part[tm][j][x] (24 KB, reuses smem; all GEMM reads done)
    float w2v[3][8];
#pragma unroll
    for (int j = 0; j < 3; ++j)
#pragma unroll
        for (int im = 0; im < 8; ++im) {
            int m = (im < 4) ? (tm * 4 + im) : (64 + tm * 4 + im - 4);
            w2v[j][im] = w2[j * NMLP + m];
        }
#pragma unroll
    for (int im = 0; im < 8; ++im)
#pragma unroll
        for (int ix = 0; ix < 8; ++ix) acc[im][ix] = fmaxf(acc[im][ix], 0.f);
#pragma unroll
    for (int j = 0; j < 3; ++j) {
#pragma unroll
        for (int half = 0; half < 2; ++half) {   // x = half*64 + tx*4..+3
            float4 v;
            float s0 = 0.f, s1 = 0.f, s2 = 0.f, s3 = 0.f;
#pragma unroll
            for (int im = 0; im < 8; ++im) {
                s0 = fmaf(w2v[j][im], acc[im][half * 4 + 0], s0);
                s1 = fmaf(w2v[j][im], acc[im][half * 4 + 1], s1);
                s2 = fmaf(w2v[j][im], acc[im][half * 4 + 2], s2);
                s3 = fmaf(w2v[j][im], acc[im][half * 4 + 3], s3);
            }
            v.x = s0; v.y = s1; v.z = s2; v.w = s3;
            // part[tm][j][half*64 + tx*4 .. +3]
            ((float4*)(smem + (tm * 3 + j) * 128 + half * 64))[tx] = v;
        }
    }
    __syncthreads();
#pragma unroll
    for (int r = 0; r < 2; ++r) {
        int idx = t + r * 256;
        if (idx < 384) {
            int j = idx >> 7, x = idx & 127;
            float s = b2[j];
#pragma unroll
            for (int g = 0; g < 16; ++g) s += smem[(g * 3 + j) * 128 + x];
            out[(size_t)(b * 3 + j) * HW + y * 256 + x0 + x] = s;
        }
    }
}

extern "C" void kernel_launch(void* const* d_in, const int* in_sizes, int n_in,
                              void* d_out, int out_size, void* d_ws, size_t ws_size,
                              hipStream_t stream) {
    const float* x     = (const float*)d_in[0];
    const float* fc0_w = (const float*)d_in[1];
    const float* fc0_b = (const float*)d_in[2];
    const float* swre  = (const float*)d_in[3];
    const float* swim  = (const float*)d_in[4];
    const float* ww    = (const float*)d_in[5];
    const float* wb    = (const float*)d_in[6];
    const float* fc1w  = (const float*)d_in[7];
    const float* fc1b  = (const float*)d_in[8];
    const float* fc2w  = (const float*)d_in[9];
    const float* fc2b  = (const float*)d_in[10];

    float* ws = (float*)d_ws;
    float2* tab    = (float2*)ws;                     // 512 floats
    float*  h      = ws + 512;                        // 33,554,432
    float*  T1F    = ws + 33554944;                   // 4,194,304
    float2* X      = (float2*)(ws + 37749248);        // 262,144 floats
    float2* Y      = (float2*)(ws + 38011392);        // 262,144 floats
    float*  Gq     = ws + 38273536;                   // 4,194,304
    float*  wwT    = ws + 42467840;                   // 16,384
    float*  w1T    = ws + 42484224;                   // 8,192
    float*  trig   = ws + 42492416;                   // 8,192
    float*  trigFT = ws + 42500608;                   // 8,192

    k_table<<<dim3(1), dim3(256), 0, stream>>>(tab);
    k_prep0<<<dim3(160), dim3(256), 0, stream>>>(tab, fc1w, ww, trig, trigFT, w1T, wwT);
    k_fc0<<<dim3(2048), dim3(256), 0, stream>>>(x, fc0_w, fc0_b, h);

    for (int d = 0; d < NDEPTH; ++d) {
        k_fwd_y<<<dim3(512), dim3(128), 0, stream>>>(h, trigFT, T1F);
        k_fwd_x<<<dim3(512), dim3(256), 0, stream>>>(T1F, trig, X);
        k_mix<<<dim3(256), dim3(256), 0, stream>>>(X, swre + (size_t)d * C * C * 256,
                                                   swim + (size_t)d * C * C * 256, Y);
        k_invy<<<dim3(512), dim3(256), 0, stream>>>(Y, tab, Gq);
        k_final<<<dim3(4096), dim3(256), 0, stream>>>(h, Gq, wwT + d * 4096, wb + d * C, trig);
    }
    k_fc12<<<dim3(4096), dim3(256), 0, stream>>>(h, w1T, fc1b, fc2w, fc2b, (float*)d_out);
}